// Round 1
// baseline (462.868 us; speedup 1.0000x reference)
//
#include <hip/hip_runtime.h>
#include <stdint.h>

#define B_SZ   512
#define D_SENS 784
#define D_IDX  64
#define D_INT  32
#define D_OUT  10
#define M_ENT  262144
#define CHUNK  512

// ---------------- Kernel A: indexer layer + init best slots ----------------
// grid 512 (one block per batch row), block 64 threads (one per output dim)
__global__ void k_indexer(const float* __restrict__ x, const float* __restrict__ W1,
                          const float* __restrict__ b1, float* __restrict__ a_out,
                          unsigned long long* __restrict__ best) {
    __shared__ float xs[D_SENS];
    int b = blockIdx.x;
    for (int j = threadIdx.x; j < D_SENS; j += 64) xs[j] = x[b * D_SENS + j];
    if (threadIdx.x == 0) best[b] = ~0ULL;  // init argmin slot every launch
    __syncthreads();
    int i = threadIdx.x;
    const float* w = W1 + i * D_SENS;
    float a0 = 0.f, a1 = 0.f, a2 = 0.f, a3 = 0.f;
    #pragma unroll 4
    for (int j = 0; j < D_SENS; j += 4) {
        a0 += w[j + 0] * xs[j + 0];
        a1 += w[j + 1] * xs[j + 1];
        a2 += w[j + 2] * xs[j + 2];
        a3 += w[j + 3] * xs[j + 3];
    }
    float v = (a0 + a1) + (a2 + a3) + b1[i];
    a_out[b * D_IDX + i] = v > 0.f ? v : 0.f;
}

// ---------------- Kernel N: per-key squared norms ----------------
// thread per key; 16 float4 loads each
__global__ void k_norms(const float* __restrict__ keys, float* __restrict__ norms) {
    int m = blockIdx.x * 256 + threadIdx.x;
    const float4* kp = (const float4*)(keys + (size_t)m * D_IDX);
    float a0 = 0.f, a1 = 0.f, a2 = 0.f, a3 = 0.f;
    #pragma unroll
    for (int t = 0; t < 16; t += 4) {
        float4 v0 = kp[t], v1 = kp[t + 1], v2 = kp[t + 2], v3 = kp[t + 3];
        a0 += v0.x * v0.x + v0.y * v0.y + v0.z * v0.z + v0.w * v0.w;
        a1 += v1.x * v1.x + v1.y * v1.y + v1.z * v1.z + v1.w * v1.w;
        a2 += v2.x * v2.x + v2.y * v2.y + v2.z * v2.z + v2.w * v2.w;
        a3 += v3.x * v3.x + v3.y * v3.y + v3.z * v3.z + v3.w * v3.w;
    }
    norms[m] = (a0 + a1) + (a2 + a3);
}

// ---------------- Kernel B: fused distance + argmin ----------------
// grid (M/CHUNK, 2), block 256. Thread = one query; key is wave-uniform
// so key loads should lower to SMEM (s_load) and feed v_fma as the sgpr operand.
__global__ __launch_bounds__(256) void k_argmin(const float* __restrict__ keys,
                                                const float* __restrict__ norms,
                                                const float* __restrict__ a_idx,
                                                unsigned long long* __restrict__ best) {
    int q = blockIdx.y * 256 + threadIdx.x;
    float a[D_IDX];
    const float4* ap = (const float4*)(a_idx + (size_t)q * D_IDX);
    #pragma unroll
    for (int t = 0; t < 16; ++t) {
        float4 v = ap[t];
        a[4 * t + 0] = v.x; a[4 * t + 1] = v.y; a[4 * t + 2] = v.z; a[4 * t + 3] = v.w;
    }
    int m0 = blockIdx.x * CHUNK;
    float bestd = INFINITY;
    int besti = 0;
    for (int i = 0; i < CHUNK; ++i) {
        int m = m0 + i;
        const float* kp = keys + (size_t)m * D_IDX;
        float d0 = 0.f, d1 = 0.f, d2 = 0.f, d3 = 0.f;
        #pragma unroll
        for (int j = 0; j < D_IDX; j += 4) {
            d0 += kp[j + 0] * a[j + 0];
            d1 += kp[j + 1] * a[j + 1];
            d2 += kp[j + 2] * a[j + 2];
            d3 += kp[j + 3] * a[j + 3];
        }
        float dot = (d0 + d1) + (d2 + d3);
        float d = norms[m] - 2.0f * dot;
        if (d < bestd) { bestd = d; besti = m; }  // strict < keeps smallest index
    }
    // order-preserving float->uint, pack with index; atomicMin == argmin w/ first-min tiebreak
    unsigned int db = __float_as_uint(bestd);
    unsigned int okey = (db & 0x80000000u) ? ~db : (db | 0x80000000u);
    unsigned long long packed = ((unsigned long long)okey << 32) | (unsigned int)besti;
    atomicMin(best + q, packed);
}

// ---------------- Kernel C: gather + integrator + output ----------------
// block per batch row, 128 threads
__global__ void k_tail(const float* __restrict__ a_idx,
                       const unsigned long long* __restrict__ best,
                       const float* __restrict__ mem_values,
                       const float* __restrict__ W2, const float* __restrict__ b2,
                       const float* __restrict__ W3, const float* __restrict__ b3,
                       const float* __restrict__ W4, const float* __restrict__ b4,
                       float* __restrict__ out) {
    int b = blockIdx.x;
    __shared__ float xr[D_SENS];
    __shared__ float as[D_IDX];
    __shared__ float ai[D_INT];
    unsigned int idx = (unsigned int)(best[b] & 0xFFFFFFFFull);
    const float* mv = mem_values + (size_t)idx * D_SENS;
    for (int j = threadIdx.x; j < D_SENS; j += blockDim.x) xr[j] = mv[j];
    if (threadIdx.x < D_IDX) as[threadIdx.x] = a_idx[b * D_IDX + threadIdx.x];
    __syncthreads();
    if (threadIdx.x < D_INT) {
        int i = threadIdx.x;
        float acc = b2[i] + b3[i];
        const float* w2 = W2 + i * D_IDX;
        #pragma unroll 8
        for (int j = 0; j < D_IDX; ++j) acc += w2[j] * as[j];
        const float* w3 = W3 + i * D_SENS;
        float c0 = 0.f, c1 = 0.f, c2 = 0.f, c3 = 0.f;
        #pragma unroll 4
        for (int j = 0; j < D_SENS; j += 4) {
            c0 += w3[j + 0] * xr[j + 0];
            c1 += w3[j + 1] * xr[j + 1];
            c2 += w3[j + 2] * xr[j + 2];
            c3 += w3[j + 3] * xr[j + 3];
        }
        acc += (c0 + c1) + (c2 + c3);
        ai[i] = acc > 0.f ? acc : 0.f;
    }
    __syncthreads();
    if (threadIdx.x < D_OUT) {
        int i = threadIdx.x;
        float acc = b4[i];
        const float* w4 = W4 + i * D_INT;
        #pragma unroll
        for (int j = 0; j < D_INT; ++j) acc += w4[j] * ai[j];
        out[b * D_OUT + i] = acc;
    }
}

extern "C" void kernel_launch(void* const* d_in, const int* in_sizes, int n_in,
                              void* d_out, int out_size, void* d_ws, size_t ws_size,
                              hipStream_t stream) {
    const float* x_sensory  = (const float*)d_in[0];
    const float* W1         = (const float*)d_in[1];
    const float* b1         = (const float*)d_in[2];
    const float* W2         = (const float*)d_in[3];
    const float* b2         = (const float*)d_in[4];
    const float* W3         = (const float*)d_in[5];
    const float* b3         = (const float*)d_in[6];
    const float* W4         = (const float*)d_in[7];
    const float* b4         = (const float*)d_in[8];
    const float* mem_keys   = (const float*)d_in[9];
    const float* mem_values = (const float*)d_in[10];
    float* out = (float*)d_out;

    // workspace layout
    unsigned long long* best = (unsigned long long*)d_ws;                       // 512 * 8 B
    float* norms = (float*)((char*)d_ws + 4096);                                // 1 MB
    float* a_idx = (float*)((char*)d_ws + 4096 + (size_t)M_ENT * 4);            // 128 KB

    k_indexer<<<B_SZ, 64, 0, stream>>>(x_sensory, W1, b1, a_idx, best);
    k_norms<<<M_ENT / 256, 256, 0, stream>>>(mem_keys, norms);
    k_argmin<<<dim3(M_ENT / CHUNK, 2), 256, 0, stream>>>(mem_keys, norms, a_idx, best);
    k_tail<<<B_SZ, 128, 0, stream>>>(a_idx, best, mem_values, W2, b2, W3, b3, W4, b4, out);
}

// Round 3
// 138.778 us; speedup vs baseline: 3.3353x; 3.3353x over previous
//
#include <hip/hip_runtime.h>
#include <stdint.h>

#define B_SZ   512
#define D_SENS 784
#define D_IDX  64
#define D_INT  32
#define D_OUT  10
#define M_ENT  262144
#define CHUNK  512
#define MARGIN 1.5f

typedef __attribute__((ext_vector_type(8))) short bf16x8;
typedef __attribute__((ext_vector_type(4))) float f32x4;

__device__ inline unsigned short f2bf_rne(float f) {
    unsigned int u = __float_as_uint(f);
    unsigned int r = u + 0x7fffu + ((u >> 16) & 1u);
    return (unsigned short)(r >> 16);
}

// ---------------- Kernel A: indexer layer + bf16 copy + init best ----------------
__global__ void k_indexer(const float* __restrict__ x, const float* __restrict__ W1,
                          const float* __restrict__ b1, float* __restrict__ a_out,
                          unsigned short* __restrict__ a_bf,
                          unsigned long long* __restrict__ best) {
    __shared__ float xs[D_SENS];
    int b = blockIdx.x;
    for (int j = threadIdx.x; j < D_SENS; j += 64) xs[j] = x[b * D_SENS + j];
    if (threadIdx.x == 0) best[b] = ~0ULL;  // init argmin slot every launch
    __syncthreads();
    int i = threadIdx.x;
    const float* w = W1 + i * D_SENS;
    float a0 = 0.f, a1 = 0.f, a2 = 0.f, a3 = 0.f;
    #pragma unroll 4
    for (int j = 0; j < D_SENS; j += 4) {
        a0 += w[j + 0] * xs[j + 0];
        a1 += w[j + 1] * xs[j + 1];
        a2 += w[j + 2] * xs[j + 2];
        a3 += w[j + 3] * xs[j + 3];
    }
    float v = (a0 + a1) + (a2 + a3) + b1[i];
    float r = v > 0.f ? v : 0.f;
    a_out[b * D_IDX + i] = r;
    a_bf[b * D_IDX + i] = f2bf_rne(r);
}

// ---------------- Kernel CV: keys f32 -> bf16 + norms (thread per key) ----------------
__global__ __launch_bounds__(256) void k_convert(const float* __restrict__ keys,
                                                 unsigned short* __restrict__ kb,
                                                 float* __restrict__ norms) {
    int m = blockIdx.x * 256 + threadIdx.x;
    const float4* kp = (const float4*)(keys + (size_t)m * D_IDX);
    uint4 o[8];                       // 8 x 16B = 128B = 64 bf16 (was o[4]: overflow bug)
    unsigned short* os = (unsigned short*)o;
    float a0 = 0.f, a1 = 0.f, a2 = 0.f, a3 = 0.f;
    #pragma unroll
    for (int t = 0; t < 16; t += 4) {
        float4 v0 = kp[t], v1 = kp[t + 1], v2 = kp[t + 2], v3 = kp[t + 3];
        a0 += v0.x * v0.x + v0.y * v0.y + v0.z * v0.z + v0.w * v0.w;
        a1 += v1.x * v1.x + v1.y * v1.y + v1.z * v1.z + v1.w * v1.w;
        a2 += v2.x * v2.x + v2.y * v2.y + v2.z * v2.z + v2.w * v2.w;
        a3 += v3.x * v3.x + v3.y * v3.y + v3.z * v3.z + v3.w * v3.w;
        os[4*t+0]  = f2bf_rne(v0.x); os[4*t+1]  = f2bf_rne(v0.y);
        os[4*t+2]  = f2bf_rne(v0.z); os[4*t+3]  = f2bf_rne(v0.w);
        os[4*t+4]  = f2bf_rne(v1.x); os[4*t+5]  = f2bf_rne(v1.y);
        os[4*t+6]  = f2bf_rne(v1.z); os[4*t+7]  = f2bf_rne(v1.w);
        os[4*t+8]  = f2bf_rne(v2.x); os[4*t+9]  = f2bf_rne(v2.y);
        os[4*t+10] = f2bf_rne(v2.z); os[4*t+11] = f2bf_rne(v2.w);
        os[4*t+12] = f2bf_rne(v3.x); os[4*t+13] = f2bf_rne(v3.y);
        os[4*t+14] = f2bf_rne(v3.z); os[4*t+15] = f2bf_rne(v3.w);
    }
    norms[m] = (a0 + a1) + (a2 + a3);
    uint4* dst = (uint4*)(kb + (size_t)m * D_IDX);
    #pragma unroll
    for (int t = 0; t < 8; ++t) dst[t] = o[t];
}

// ---------------- Kernel S: MFMA bf16 screen ----------------
// block 256 = 4 waves; wave owns 64 keys (4 m-tiles of 16), loops all 32 q-tiles.
// mfma_f32_16x16x32_bf16: A=keys (row=lane&15, k=8*(lane>>4)+j), B=queries (col=lane&15),
// D: col(q)=lane&15, row(m)=(lane>>4)*4+reg  [m89/m91-verified layout].
// C-init = -0.5*norm  =>  acc_final = dot - norm/2  =>  min d == max acc.
__global__ __launch_bounds__(256) void k_screen(const unsigned short* __restrict__ kb,
                                                const unsigned short* __restrict__ ab,
                                                const float* __restrict__ norms,
                                                float* __restrict__ chunkmin) {
    int lane = threadIdx.x & 63;
    int wid = threadIdx.x >> 6;
    int l15 = lane & 15, lg = lane >> 4;
    int mbase = blockIdx.x * 256 + wid * 64;
    int chunk = blockIdx.x * 4 + wid;

    bf16x8 kf[4][2];
    #pragma unroll
    for (int t = 0; t < 4; ++t)
        #pragma unroll
        for (int kk = 0; kk < 2; ++kk)
            kf[t][kk] = *(const bf16x8*)(kb + (size_t)(mbase + 16*t + l15) * D_IDX + kk*32 + lg*8);

    float nrm[4][4];
    #pragma unroll
    for (int t = 0; t < 4; ++t)
        #pragma unroll
        for (int r = 0; r < 4; ++r)
            nrm[t][r] = -0.5f * norms[mbase + 16*t + lg*4 + r];

    bf16x8 q0 = *(const bf16x8*)(ab + (size_t)l15 * D_IDX + lg*8);
    bf16x8 q1 = *(const bf16x8*)(ab + (size_t)l15 * D_IDX + 32 + lg*8);

    for (int qt = 0; qt < 32; ++qt) {
        bf16x8 c0 = q0, c1 = q1;
        if (qt < 31) {
            q0 = *(const bf16x8*)(ab + (size_t)((qt+1)*16 + l15) * D_IDX + lg*8);
            q1 = *(const bf16x8*)(ab + (size_t)((qt+1)*16 + l15) * D_IDX + 32 + lg*8);
        }
        f32x4 acc[4];
        #pragma unroll
        for (int t = 0; t < 4; ++t)
            acc[t] = (f32x4){nrm[t][0], nrm[t][1], nrm[t][2], nrm[t][3]};
        #pragma unroll
        for (int t = 0; t < 4; ++t)
            acc[t] = __builtin_amdgcn_mfma_f32_16x16x32_bf16(kf[t][0], c0, acc[t], 0, 0, 0);
        #pragma unroll
        for (int t = 0; t < 4; ++t)
            acc[t] = __builtin_amdgcn_mfma_f32_16x16x32_bf16(kf[t][1], c1, acc[t], 0, 0, 0);

        float t0 = fmaxf(fmaxf(acc[0][0], acc[0][1]), fmaxf(acc[0][2], acc[0][3]));
        float t1 = fmaxf(fmaxf(acc[1][0], acc[1][1]), fmaxf(acc[1][2], acc[1][3]));
        float t2 = fmaxf(fmaxf(acc[2][0], acc[2][1]), fmaxf(acc[2][2], acc[2][3]));
        float t3 = fmaxf(fmaxf(acc[3][0], acc[3][1]), fmaxf(acc[3][2], acc[3][3]));
        float mx = fmaxf(fmaxf(t0, t1), fmaxf(t2, t3));
        mx = fmaxf(mx, __shfl_xor(mx, 16, 64));
        mx = fmaxf(mx, __shfl_xor(mx, 32, 64));
        if (lane < 16)
            chunkmin[(size_t)(qt*16 + lane) * (M_ENT/64) + chunk] = -2.0f * mx;
    }
}

// ---------------- Kernel R: exact fp32 refine over candidate chunks ----------------
__global__ __launch_bounds__(256) void k_refine(const float* __restrict__ chunkmin,
                                                const float* __restrict__ keys,
                                                const float* __restrict__ norms,
                                                const float* __restrict__ a_idx,
                                                unsigned long long* __restrict__ best) {
    int q = blockIdx.x, tid = threadIdx.x;
    __shared__ float a_s[D_IDX];
    __shared__ float red[256];
    __shared__ int list[256];
    __shared__ int cnt;
    if (tid < D_IDX) a_s[tid] = a_idx[q * D_IDX + tid];
    if (tid == 0) cnt = 0;
    const float* wrow = chunkmin + (size_t)q * (M_ENT/64);
    float v[16];
    float lm = INFINITY;
    #pragma unroll
    for (int i = 0; i < 16; ++i) { v[i] = wrow[tid + 256*i]; lm = fminf(lm, v[i]); }
    red[tid] = lm;
    __syncthreads();
    for (int s = 128; s > 0; s >>= 1) {
        if (tid < s) red[tid] = fminf(red[tid], red[tid + s]);
        __syncthreads();
    }
    float thrv = red[0] + MARGIN;
    #pragma unroll
    for (int i = 0; i < 16; ++i)
        if (v[i] <= thrv) { int p = atomicAdd(&cnt, 1); if (p < 256) list[p] = tid + 256*i; }
    __syncthreads();
    int n = cnt > 256 ? 256 : cnt;
    int kq = tid >> 2, qtr = tid & 3;
    for (int e = 0; e < n; ++e) {
        int m = list[e] * 64 + kq;
        const float4* kp = (const float4*)(keys + (size_t)m * D_IDX + qtr * 16);
        const float4* av = (const float4*)(a_s + qtr * 16);
        float p = 0.f;
        #pragma unroll
        for (int j = 0; j < 4; ++j) {
            float4 kv = kp[j], av4 = av[j];
            p += kv.x*av4.x + kv.y*av4.y + kv.z*av4.z + kv.w*av4.w;
        }
        p += __shfl_xor(p, 1, 64);
        p += __shfl_xor(p, 2, 64);
        if (qtr == 0) {
            float d = norms[m] - 2.0f * p;
            unsigned int db = __float_as_uint(d);
            unsigned int ok = (db & 0x80000000u) ? ~db : (db | 0x80000000u);
            atomicMin(best + q, ((unsigned long long)ok << 32) | (unsigned int)m);
        }
    }
}

// ---------------- Fallback fp32 kernels (round-1, proven) ----------------
__global__ void k_norms(const float* __restrict__ keys, float* __restrict__ norms) {
    int m = blockIdx.x * 256 + threadIdx.x;
    const float4* kp = (const float4*)(keys + (size_t)m * D_IDX);
    float a0 = 0.f, a1 = 0.f, a2 = 0.f, a3 = 0.f;
    #pragma unroll
    for (int t = 0; t < 16; t += 4) {
        float4 v0 = kp[t], v1 = kp[t + 1], v2 = kp[t + 2], v3 = kp[t + 3];
        a0 += v0.x * v0.x + v0.y * v0.y + v0.z * v0.z + v0.w * v0.w;
        a1 += v1.x * v1.x + v1.y * v1.y + v1.z * v1.z + v1.w * v1.w;
        a2 += v2.x * v2.x + v2.y * v2.y + v2.z * v2.z + v2.w * v2.w;
        a3 += v3.x * v3.x + v3.y * v3.y + v3.z * v3.z + v3.w * v3.w;
    }
    norms[m] = (a0 + a1) + (a2 + a3);
}

__global__ __launch_bounds__(256) void k_argmin(const float* __restrict__ keys,
                                                const float* __restrict__ norms,
                                                const float* __restrict__ a_idx,
                                                unsigned long long* __restrict__ best) {
    int q = blockIdx.y * 256 + threadIdx.x;
    float a[D_IDX];
    const float4* ap = (const float4*)(a_idx + (size_t)q * D_IDX);
    #pragma unroll
    for (int t = 0; t < 16; ++t) {
        float4 v = ap[t];
        a[4*t+0] = v.x; a[4*t+1] = v.y; a[4*t+2] = v.z; a[4*t+3] = v.w;
    }
    int m0 = blockIdx.x * CHUNK;
    float bestd = INFINITY;
    int besti = 0;
    for (int i = 0; i < CHUNK; ++i) {
        int m = m0 + i;
        const float* kp = keys + (size_t)m * D_IDX;
        float d0 = 0.f, d1 = 0.f, d2 = 0.f, d3 = 0.f;
        #pragma unroll
        for (int j = 0; j < D_IDX; j += 4) {
            d0 += kp[j+0] * a[j+0];
            d1 += kp[j+1] * a[j+1];
            d2 += kp[j+2] * a[j+2];
            d3 += kp[j+3] * a[j+3];
        }
        float dot = (d0 + d1) + (d2 + d3);
        float d = norms[m] - 2.0f * dot;
        if (d < bestd) { bestd = d; besti = m; }
    }
    unsigned int db = __float_as_uint(bestd);
    unsigned int okey = (db & 0x80000000u) ? ~db : (db | 0x80000000u);
    unsigned long long packed = ((unsigned long long)okey << 32) | (unsigned int)besti;
    atomicMin(best + q, packed);
}

// ---------------- Kernel C: gather + integrator + output ----------------
__global__ void k_tail(const float* __restrict__ a_idx,
                       const unsigned long long* __restrict__ best,
                       const float* __restrict__ mem_values,
                       const float* __restrict__ W2, const float* __restrict__ b2,
                       const float* __restrict__ W3, const float* __restrict__ b3,
                       const float* __restrict__ W4, const float* __restrict__ b4,
                       float* __restrict__ out) {
    int b = blockIdx.x;
    __shared__ float xr[D_SENS];
    __shared__ float as[D_IDX];
    __shared__ float ai[D_INT];
    unsigned int idx = (unsigned int)(best[b] & 0xFFFFFFFFull);
    const float* mv = mem_values + (size_t)idx * D_SENS;
    for (int j = threadIdx.x; j < D_SENS; j += blockDim.x) xr[j] = mv[j];
    if (threadIdx.x < D_IDX) as[threadIdx.x] = a_idx[b * D_IDX + threadIdx.x];
    __syncthreads();
    if (threadIdx.x < D_INT) {
        int i = threadIdx.x;
        float acc = b2[i] + b3[i];
        const float* w2 = W2 + i * D_IDX;
        #pragma unroll 8
        for (int j = 0; j < D_IDX; ++j) acc += w2[j] * as[j];
        const float* w3 = W3 + i * D_SENS;
        float c0 = 0.f, c1 = 0.f, c2 = 0.f, c3 = 0.f;
        #pragma unroll 4
        for (int j = 0; j < D_SENS; j += 4) {
            c0 += w3[j+0] * xr[j+0];
            c1 += w3[j+1] * xr[j+1];
            c2 += w3[j+2] * xr[j+2];
            c3 += w3[j+3] * xr[j+3];
        }
        acc += (c0 + c1) + (c2 + c3);
        ai[i] = acc > 0.f ? acc : 0.f;
    }
    __syncthreads();
    if (threadIdx.x < D_OUT) {
        int i = threadIdx.x;
        float acc = b4[i];
        const float* w4 = W4 + i * D_INT;
        #pragma unroll
        for (int j = 0; j < D_INT; ++j) acc += w4[j] * ai[j];
        out[b * D_OUT + i] = acc;
    }
}

extern "C" void kernel_launch(void* const* d_in, const int* in_sizes, int n_in,
                              void* d_out, int out_size, void* d_ws, size_t ws_size,
                              hipStream_t stream) {
    const float* x_sensory  = (const float*)d_in[0];
    const float* W1         = (const float*)d_in[1];
    const float* b1         = (const float*)d_in[2];
    const float* W2         = (const float*)d_in[3];
    const float* b2         = (const float*)d_in[4];
    const float* W3         = (const float*)d_in[5];
    const float* b3         = (const float*)d_in[6];
    const float* W4         = (const float*)d_in[7];
    const float* b4         = (const float*)d_in[8];
    const float* mem_keys   = (const float*)d_in[9];
    const float* mem_values = (const float*)d_in[10];
    float* out = (float*)d_out;

    // fast-path workspace layout
    char* ws = (char*)d_ws;
    unsigned long long* best = (unsigned long long*)ws;              // 4 KB
    float*          a_idx    = (float*)(ws + 4096);                  // 128 KB
    unsigned short* a_bf     = (unsigned short*)(ws + 135168);       // 64 KB
    float*          norms    = (float*)(ws + 200704);                // 1 MB
    float*          chunkmin = (float*)(ws + 1249280);               // 8 MB
    unsigned short* keys_bf  = (unsigned short*)(ws + 9637888);      // 32 MB
    const size_t NEEDED = 43192320;

    if (ws_size >= NEEDED) {
        k_indexer<<<B_SZ, 64, 0, stream>>>(x_sensory, W1, b1, a_idx, a_bf, best);
        k_convert<<<M_ENT/256, 256, 0, stream>>>(mem_keys, keys_bf, norms);
        k_screen<<<M_ENT/256, 256, 0, stream>>>(keys_bf, a_bf, norms, chunkmin);
        k_refine<<<B_SZ, 256, 0, stream>>>(chunkmin, mem_keys, norms, a_idx, best);
    } else {
        // fallback: fp32 path (round-1 layout)
        float* f_norms = (float*)(ws + 4096);
        float* f_a_idx = (float*)(ws + 4096 + (size_t)M_ENT * 4);
        unsigned short* dummy_bf = (unsigned short*)(ws + 4096 + (size_t)M_ENT * 4 + 131072);
        k_indexer<<<B_SZ, 64, 0, stream>>>(x_sensory, W1, b1, f_a_idx, dummy_bf, best);
        k_norms<<<M_ENT/256, 256, 0, stream>>>(mem_keys, f_norms);
        k_argmin<<<dim3(M_ENT/CHUNK, 2), 256, 0, stream>>>(mem_keys, f_norms, f_a_idx, best);
        float* use_a = f_a_idx;
        k_tail<<<B_SZ, 128, 0, stream>>>(use_a, best, mem_values, W2, b2, W3, b3, W4, b4, out);
        return;
    }
    k_tail<<<B_SZ, 128, 0, stream>>>(a_idx, best, mem_values, W2, b2, W3, b3, W4, b4, out);
}

// Round 4
// 122.530 us; speedup vs baseline: 3.7776x; 1.1326x over previous
//
#include <hip/hip_runtime.h>
#include <stdint.h>

#define B_SZ   512
#define D_SENS 784
#define D_IDX  64
#define D_INT  32
#define D_OUT  10
#define M_ENT  262144
#define NCHUNK (M_ENT / 64)
#define MARGIN 1.5f

typedef __attribute__((ext_vector_type(8))) short bf16x8;
typedef __attribute__((ext_vector_type(4))) float f32x4;

__device__ inline unsigned short f2bf_rne(float f) {
    unsigned int u = __float_as_uint(f);
    unsigned int r = u + 0x7fffu + ((u >> 16) & 1u);
    return (unsigned short)(r >> 16);
}

// ---------------- Kernel T: transpose W1, W2, W3 for coalesced reads ----------------
// W1[64,784]->W1T[784,64], W2[32,64]->W2T[64,32], W3[32,784]->W3T[784,32]
__global__ __launch_bounds__(256) void k_transpose(const float* __restrict__ W1,
                                                   const float* __restrict__ W2,
                                                   const float* __restrict__ W3,
                                                   float* __restrict__ W1T,
                                                   float* __restrict__ W2T,
                                                   float* __restrict__ W3T) {
    int idx = blockIdx.x * 256 + threadIdx.x;
    if (idx < 50176) {                       // 784*64
        int j = idx >> 6, i = idx & 63;
        W1T[idx] = W1[i * D_SENS + j];
    }
    int i2 = idx - 50176;
    if (i2 >= 0 && i2 < 2048) {              // 64*32
        int j = i2 >> 5, i = i2 & 31;
        W2T[i2] = W2[i * D_IDX + j];
    }
    int i3 = idx - 52224;
    if (i3 >= 0 && i3 < 25088) {             // 784*32
        int j = i3 >> 5, i = i3 & 31;
        W3T[i3] = W3[i * D_SENS + j];
    }
}

// ---------------- Kernel A: indexer layer (coalesced W1T) + bf16 copy + init best ----
// 512 blocks x 256 threads; thread (i=tid&63, part=tid>>6) does a quarter of K.
__global__ __launch_bounds__(256) void k_indexer(const float* __restrict__ x,
                                                 const float* __restrict__ w1t,
                                                 const float* __restrict__ b1,
                                                 float* __restrict__ a_out,
                                                 unsigned short* __restrict__ a_bf,
                                                 unsigned long long* __restrict__ best) {
    int b = blockIdx.x, tid = threadIdx.x;
    __shared__ float xs[D_SENS];
    __shared__ float part[4][D_IDX];
    for (int j = tid; j < D_SENS; j += 256) xs[j] = x[b * D_SENS + j];
    if (tid == 0) best[b] = ~0ULL;
    __syncthreads();
    int i = tid & 63, prt = tid >> 6;
    int j0 = prt * 196;
    float c0 = 0.f, c1 = 0.f, c2 = 0.f, c3 = 0.f;
    #pragma unroll 4
    for (int jj = 0; jj < 196; jj += 4) {
        c0 += w1t[(j0 + jj + 0) * 64 + i] * xs[j0 + jj + 0];
        c1 += w1t[(j0 + jj + 1) * 64 + i] * xs[j0 + jj + 1];
        c2 += w1t[(j0 + jj + 2) * 64 + i] * xs[j0 + jj + 2];
        c3 += w1t[(j0 + jj + 3) * 64 + i] * xs[j0 + jj + 3];
    }
    part[prt][i] = (c0 + c1) + (c2 + c3);
    __syncthreads();
    if (tid < D_IDX) {
        float v = part[0][tid] + part[1][tid] + part[2][tid] + part[3][tid] + b1[tid];
        float r = v > 0.f ? v : 0.f;
        a_out[b * D_IDX + tid] = r;
        a_bf[b * D_IDX + tid] = f2bf_rne(r);
    }
}

// ---------------- Kernel S: fused convert + norms + MFMA bf16 screen ----------------
// block 256 = 4 waves; wave owns 64 keys (4 m-tiles of 16), loops all 32 q-tiles.
// Reads fp32 keys directly, converts to bf16 fragments in-register, computes
// -0.5*norm in-register (shfl_xor reduce over lane-groups + bpermute redistribute).
// mfma_f32_16x16x32_bf16: A=keys (row=lane&15, k=8*(lane>>4)+j), B=queries (col=lane&15),
// D: col(q)=lane&15, row(m)=(lane>>4)*4+reg  [validated empirically in round 3].
__global__ __launch_bounds__(256) void k_screen(const float* __restrict__ keys,
                                                const unsigned short* __restrict__ ab,
                                                float* __restrict__ chunkmin) {
    int lane = threadIdx.x & 63;
    int wid = threadIdx.x >> 6;
    int l15 = lane & 15, lg = lane >> 4;
    int mbase = blockIdx.x * 256 + wid * 64;
    int chunk = blockIdx.x * 4 + wid;

    bf16x8 kf[4][2];
    float nrm[4][4];
    #pragma unroll
    for (int t = 0; t < 4; ++t) {
        const float* rowp = keys + (size_t)(mbase + 16 * t + l15) * D_IDX;
        float4 f0 = *(const float4*)(rowp + lg * 8);
        float4 f1 = *(const float4*)(rowp + lg * 8 + 4);
        float4 f2 = *(const float4*)(rowp + 32 + lg * 8);
        float4 f3 = *(const float4*)(rowp + 32 + lg * 8 + 4);
        union { bf16x8 v; unsigned short s[8]; } p0, p1;
        p0.s[0] = f2bf_rne(f0.x); p0.s[1] = f2bf_rne(f0.y);
        p0.s[2] = f2bf_rne(f0.z); p0.s[3] = f2bf_rne(f0.w);
        p0.s[4] = f2bf_rne(f1.x); p0.s[5] = f2bf_rne(f1.y);
        p0.s[6] = f2bf_rne(f1.z); p0.s[7] = f2bf_rne(f1.w);
        p1.s[0] = f2bf_rne(f2.x); p1.s[1] = f2bf_rne(f2.y);
        p1.s[2] = f2bf_rne(f2.z); p1.s[3] = f2bf_rne(f2.w);
        p1.s[4] = f2bf_rne(f3.x); p1.s[5] = f2bf_rne(f3.y);
        p1.s[6] = f2bf_rne(f3.z); p1.s[7] = f2bf_rne(f3.w);
        kf[t][0] = p0.v; kf[t][1] = p1.v;
        float s = f0.x*f0.x + f0.y*f0.y + f0.z*f0.z + f0.w*f0.w
                + f1.x*f1.x + f1.y*f1.y + f1.z*f1.z + f1.w*f1.w
                + f2.x*f2.x + f2.y*f2.y + f2.z*f2.z + f2.w*f2.w
                + f3.x*f3.x + f3.y*f3.y + f3.z*f3.z + f3.w*f3.w;
        s += __shfl_xor(s, 16, 64);
        s += __shfl_xor(s, 32, 64);   // full norm of row (mbase+16t+l15), replicated over lg
        s *= -0.5f;
        #pragma unroll
        for (int r = 0; r < 4; ++r)
            nrm[t][r] = __shfl(s, lg * 4 + r, 64);   // row lg*4+r held by lane (lg*4+r)
    }

    bf16x8 q0 = *(const bf16x8*)(ab + (size_t)l15 * D_IDX + lg * 8);
    bf16x8 q1 = *(const bf16x8*)(ab + (size_t)l15 * D_IDX + 32 + lg * 8);

    for (int qt = 0; qt < 32; ++qt) {
        bf16x8 c0 = q0, c1 = q1;
        if (qt < 31) {
            q0 = *(const bf16x8*)(ab + (size_t)((qt + 1) * 16 + l15) * D_IDX + lg * 8);
            q1 = *(const bf16x8*)(ab + (size_t)((qt + 1) * 16 + l15) * D_IDX + 32 + lg * 8);
        }
        f32x4 acc[4];
        #pragma unroll
        for (int t = 0; t < 4; ++t)
            acc[t] = (f32x4){nrm[t][0], nrm[t][1], nrm[t][2], nrm[t][3]};
        #pragma unroll
        for (int t = 0; t < 4; ++t)
            acc[t] = __builtin_amdgcn_mfma_f32_16x16x32_bf16(kf[t][0], c0, acc[t], 0, 0, 0);
        #pragma unroll
        for (int t = 0; t < 4; ++t)
            acc[t] = __builtin_amdgcn_mfma_f32_16x16x32_bf16(kf[t][1], c1, acc[t], 0, 0, 0);

        // max-reduce 16 values via v_max3-friendly triples
        float t0 = fmaxf(fmaxf(acc[0][0], acc[0][1]), acc[0][2]);
        float t1 = fmaxf(fmaxf(acc[0][3], acc[1][0]), acc[1][1]);
        float t2 = fmaxf(fmaxf(acc[1][2], acc[1][3]), acc[2][0]);
        float t3 = fmaxf(fmaxf(acc[2][1], acc[2][2]), acc[2][3]);
        float t4 = fmaxf(fmaxf(acc[3][0], acc[3][1]), acc[3][2]);
        float mx = fmaxf(fmaxf(fmaxf(t0, t1), fmaxf(t2, t3)), fmaxf(t4, acc[3][3]));
        mx = fmaxf(mx, __shfl_xor(mx, 16, 64));
        mx = fmaxf(mx, __shfl_xor(mx, 32, 64));
        if (lane < 16)
            chunkmin[(size_t)(qt * 16 + lane) * NCHUNK + chunk] = -2.0f * mx;
    }
}

// ---------------- Kernel R: exact fp32 refine (norms computed inline) ----------------
__global__ __launch_bounds__(256) void k_refine(const float* __restrict__ chunkmin,
                                                const float* __restrict__ keys,
                                                const float* __restrict__ a_idx,
                                                unsigned long long* __restrict__ best) {
    int q = blockIdx.x, tid = threadIdx.x;
    __shared__ float a_s[D_IDX];
    __shared__ float red[256];
    __shared__ int list[256];
    __shared__ int cnt;
    if (tid < D_IDX) a_s[tid] = a_idx[q * D_IDX + tid];
    if (tid == 0) cnt = 0;
    const float* wrow = chunkmin + (size_t)q * NCHUNK;
    float v[16];
    float lm = INFINITY;
    #pragma unroll
    for (int i = 0; i < 16; ++i) { v[i] = wrow[tid + 256 * i]; lm = fminf(lm, v[i]); }
    red[tid] = lm;
    __syncthreads();
    for (int s = 128; s > 0; s >>= 1) {
        if (tid < s) red[tid] = fminf(red[tid], red[tid + s]);
        __syncthreads();
    }
    float thrv = red[0] + MARGIN;
    #pragma unroll
    for (int i = 0; i < 16; ++i)
        if (v[i] <= thrv) { int p = atomicAdd(&cnt, 1); if (p < 256) list[p] = tid + 256 * i; }
    __syncthreads();
    int n = cnt > 256 ? 256 : cnt;
    int kq = tid >> 2, qtr = tid & 3;
    for (int e = 0; e < n; ++e) {
        int m = list[e] * 64 + kq;
        const float4* kp = (const float4*)(keys + (size_t)m * D_IDX + qtr * 16);
        const float4* av = (const float4*)(a_s + qtr * 16);
        float p = 0.f, p2 = 0.f;
        #pragma unroll
        for (int j = 0; j < 4; ++j) {
            float4 kv = kp[j], av4 = av[j];
            p  += kv.x * av4.x + kv.y * av4.y + kv.z * av4.z + kv.w * av4.w;
            p2 += kv.x * kv.x + kv.y * kv.y + kv.z * kv.z + kv.w * kv.w;
        }
        p  += __shfl_xor(p, 1, 64);  p  += __shfl_xor(p, 2, 64);
        p2 += __shfl_xor(p2, 1, 64); p2 += __shfl_xor(p2, 2, 64);
        if (qtr == 0) {
            float d = p2 - 2.0f * p;
            unsigned int db = __float_as_uint(d);
            unsigned int ok = (db & 0x80000000u) ? ~db : (db | 0x80000000u);
            atomicMin(best + q, ((unsigned long long)ok << 32) | (unsigned int)m);
        }
    }
}

// ---------------- Kernel C: gather + integrator + output (coalesced W2T/W3T) --------
__global__ __launch_bounds__(128) void k_tail(const float* __restrict__ a_idx,
                                              const unsigned long long* __restrict__ best,
                                              const float* __restrict__ mem_values,
                                              const float* __restrict__ w2t,
                                              const float* __restrict__ b2,
                                              const float* __restrict__ w3t,
                                              const float* __restrict__ b3,
                                              const float* __restrict__ W4,
                                              const float* __restrict__ b4,
                                              float* __restrict__ out) {
    int b = blockIdx.x, tid = threadIdx.x;
    __shared__ float xr[D_SENS];
    __shared__ float as[D_IDX];
    __shared__ float part[4][D_INT];
    __shared__ float ai[D_INT];
    unsigned int idx = (unsigned int)(best[b] & 0xFFFFFFFFull);
    const float* mv = mem_values + (size_t)idx * D_SENS;
    for (int j = tid; j < D_SENS; j += 128) xr[j] = mv[j];
    if (tid < D_IDX) as[tid] = a_idx[b * D_IDX + tid];
    __syncthreads();
    int i = tid & 31, prt = tid >> 5;
    int j0 = prt * 196;
    float c0 = 0.f, c1 = 0.f;
    #pragma unroll 2
    for (int jj = 0; jj < 196; jj += 2) {
        c0 += w3t[(j0 + jj + 0) * 32 + i] * xr[j0 + jj + 0];
        c1 += w3t[(j0 + jj + 1) * 32 + i] * xr[j0 + jj + 1];
    }
    float c2 = 0.f;
    int j2 = prt * 16;
    #pragma unroll
    for (int jj = 0; jj < 16; ++jj) c2 += w2t[(j2 + jj) * 32 + i] * as[j2 + jj];
    part[prt][i] = (c0 + c1) + c2;
    __syncthreads();
    if (tid < D_INT) {
        float acc = part[0][tid] + part[1][tid] + part[2][tid] + part[3][tid] + b2[tid] + b3[tid];
        ai[tid] = acc > 0.f ? acc : 0.f;
    }
    __syncthreads();
    if (tid < D_OUT) {
        float acc = b4[tid];
        const float* w4 = W4 + tid * D_INT;
        #pragma unroll
        for (int j = 0; j < D_INT; ++j) acc += w4[j] * ai[j];
        out[b * D_OUT + tid] = acc;
    }
}

// ---------------- Fallback fp32 kernels (proven round-1 structure) ----------------
__global__ void k_norms(const float* __restrict__ keys, float* __restrict__ norms) {
    int m = blockIdx.x * 256 + threadIdx.x;
    const float4* kp = (const float4*)(keys + (size_t)m * D_IDX);
    float a0 = 0.f, a1 = 0.f, a2 = 0.f, a3 = 0.f;
    #pragma unroll
    for (int t = 0; t < 16; t += 4) {
        float4 v0 = kp[t], v1 = kp[t + 1], v2 = kp[t + 2], v3 = kp[t + 3];
        a0 += v0.x * v0.x + v0.y * v0.y + v0.z * v0.z + v0.w * v0.w;
        a1 += v1.x * v1.x + v1.y * v1.y + v1.z * v1.z + v1.w * v1.w;
        a2 += v2.x * v2.x + v2.y * v2.y + v2.z * v2.z + v2.w * v2.w;
        a3 += v3.x * v3.x + v3.y * v3.y + v3.z * v3.z + v3.w * v3.w;
    }
    norms[m] = (a0 + a1) + (a2 + a3);
}

__global__ __launch_bounds__(256) void k_argmin(const float* __restrict__ keys,
                                                const float* __restrict__ norms,
                                                const float* __restrict__ a_idx,
                                                unsigned long long* __restrict__ best) {
    int q = blockIdx.y * 256 + threadIdx.x;
    float a[D_IDX];
    const float4* ap = (const float4*)(a_idx + (size_t)q * D_IDX);
    #pragma unroll
    for (int t = 0; t < 16; ++t) {
        float4 v = ap[t];
        a[4*t+0] = v.x; a[4*t+1] = v.y; a[4*t+2] = v.z; a[4*t+3] = v.w;
    }
    int m0 = blockIdx.x * 512;
    float bestd = INFINITY;
    int besti = 0;
    for (int i = 0; i < 512; ++i) {
        int m = m0 + i;
        const float* kp = keys + (size_t)m * D_IDX;
        float d0 = 0.f, d1 = 0.f, d2 = 0.f, d3 = 0.f;
        #pragma unroll
        for (int j = 0; j < D_IDX; j += 4) {
            d0 += kp[j+0] * a[j+0];
            d1 += kp[j+1] * a[j+1];
            d2 += kp[j+2] * a[j+2];
            d3 += kp[j+3] * a[j+3];
        }
        float dot = (d0 + d1) + (d2 + d3);
        float d = norms[m] - 2.0f * dot;
        if (d < bestd) { bestd = d; besti = m; }
    }
    unsigned int db = __float_as_uint(bestd);
    unsigned int okey = (db & 0x80000000u) ? ~db : (db | 0x80000000u);
    atomicMin(best + q, ((unsigned long long)okey << 32) | (unsigned int)besti);
}

extern "C" void kernel_launch(void* const* d_in, const int* in_sizes, int n_in,
                              void* d_out, int out_size, void* d_ws, size_t ws_size,
                              hipStream_t stream) {
    const float* x_sensory  = (const float*)d_in[0];
    const float* W1         = (const float*)d_in[1];
    const float* b1         = (const float*)d_in[2];
    const float* W2         = (const float*)d_in[3];
    const float* b2         = (const float*)d_in[4];
    const float* W3         = (const float*)d_in[5];
    const float* b3         = (const float*)d_in[6];
    const float* W4         = (const float*)d_in[7];
    const float* b4         = (const float*)d_in[8];
    const float* mem_keys   = (const float*)d_in[9];
    const float* mem_values = (const float*)d_in[10];
    float* out = (float*)d_out;

    // workspace layout
    char* ws = (char*)d_ws;
    unsigned long long* best = (unsigned long long*)ws;          // 4 KB @ 0
    float*          a_idx    = (float*)(ws + 4096);              // 128 KB
    unsigned short* a_bf     = (unsigned short*)(ws + 135168);   // 64 KB
    float*          W1T      = (float*)(ws + 200704);            // 196 KB
    float*          W2T      = (float*)(ws + 401408);            // 8 KB
    float*          W3T      = (float*)(ws + 409600);            // 98 KB
    float*          chunkmin = (float*)(ws + 524288);            // 8 MB
    const size_t NEEDED = 524288 + (size_t)B_SZ * NCHUNK * 4;    // ~8.9 MB

    if (ws_size >= NEEDED) {
        k_transpose<<<302, 256, 0, stream>>>(W1, W2, W3, W1T, W2T, W3T);
        k_indexer<<<B_SZ, 256, 0, stream>>>(x_sensory, W1T, b1, a_idx, a_bf, best);
        k_screen<<<M_ENT / 256, 256, 0, stream>>>(mem_keys, a_bf, chunkmin);
        k_refine<<<B_SZ, 256, 0, stream>>>(chunkmin, mem_keys, a_idx, best);
        k_tail<<<B_SZ, 128, 0, stream>>>(a_idx, best, mem_values, W2T, b2, W3T, b3, W4, b4, out);
    } else {
        // fallback: fp32 brute-force path (needs only ~1.6 MB)
        float* norms = (float*)(ws + 524288);                    // 1 MB
        k_transpose<<<302, 256, 0, stream>>>(W1, W2, W3, W1T, W2T, W3T);
        k_indexer<<<B_SZ, 256, 0, stream>>>(x_sensory, W1T, b1, a_idx, a_bf, best);
        k_norms<<<M_ENT / 256, 256, 0, stream>>>(mem_keys, norms);
        k_argmin<<<dim3(M_ENT / 512, 2), 256, 0, stream>>>(mem_keys, norms, a_idx, best);
        k_tail<<<B_SZ, 128, 0, stream>>>(a_idx, best, mem_values, W2T, b2, W3T, b3, W4, b4, out);
    }
}

// Round 5
// 108.794 us; speedup vs baseline: 4.2545x; 1.1263x over previous
//
#include <hip/hip_runtime.h>
#include <stdint.h>

#define B_SZ   512
#define D_SENS 784
#define D_IDX  64
#define D_INT  32
#define D_OUT  10
#define M_ENT  262144
#define NCHUNK (M_ENT / 64)
#define MARGIN 1.5f

typedef __attribute__((ext_vector_type(8))) short bf16x8;
typedef __attribute__((ext_vector_type(4))) float f32x4;

__device__ inline unsigned short f2bf_rne(float f) {
    unsigned int u = __float_as_uint(f);
    unsigned int r = u + 0x7fffu + ((u >> 16) & 1u);
    return (unsigned short)(r >> 16);
}
__device__ inline unsigned int pack2bf(float lo, float hi) {
    return (unsigned int)f2bf_rne(lo) | ((unsigned int)f2bf_rne(hi) << 16);
}

// ---------------- Kernel T: transpose W1, W2, W3 for coalesced reads ----------------
__global__ __launch_bounds__(256) void k_transpose(const float* __restrict__ W1,
                                                   const float* __restrict__ W2,
                                                   const float* __restrict__ W3,
                                                   float* __restrict__ W1T,
                                                   float* __restrict__ W2T,
                                                   float* __restrict__ W3T) {
    int idx = blockIdx.x * 256 + threadIdx.x;
    if (idx < 50176) {                       // 784*64
        int j = idx >> 6, i = idx & 63;
        W1T[idx] = W1[i * D_SENS + j];
    }
    int i2 = idx - 50176;
    if (i2 >= 0 && i2 < 2048) {              // 64*32
        int j = i2 >> 5, i = i2 & 31;
        W2T[i2] = W2[i * D_IDX + j];
    }
    int i3 = idx - 52224;
    if (i3 >= 0 && i3 < 25088) {             // 784*32
        int j = i3 >> 5, i = i3 & 31;
        W3T[i3] = W3[i * D_SENS + j];
    }
}

// ---------------- Kernel A: indexer layer (coalesced W1T) + bf16 copy + init best ----
__global__ __launch_bounds__(256) void k_indexer(const float* __restrict__ x,
                                                 const float* __restrict__ w1t,
                                                 const float* __restrict__ b1,
                                                 float* __restrict__ a_out,
                                                 unsigned short* __restrict__ a_bf,
                                                 unsigned long long* __restrict__ best) {
    int b = blockIdx.x, tid = threadIdx.x;
    __shared__ float xs[D_SENS];
    __shared__ float part[4][D_IDX];
    for (int j = tid; j < D_SENS; j += 256) xs[j] = x[b * D_SENS + j];
    if (tid == 0) best[b] = ~0ULL;
    __syncthreads();
    int i = tid & 63, prt = tid >> 6;
    int j0 = prt * 196;
    float c0 = 0.f, c1 = 0.f, c2 = 0.f, c3 = 0.f;
    #pragma unroll 4
    for (int jj = 0; jj < 196; jj += 4) {
        c0 += w1t[(j0 + jj + 0) * 64 + i] * xs[j0 + jj + 0];
        c1 += w1t[(j0 + jj + 1) * 64 + i] * xs[j0 + jj + 1];
        c2 += w1t[(j0 + jj + 2) * 64 + i] * xs[j0 + jj + 2];
        c3 += w1t[(j0 + jj + 3) * 64 + i] * xs[j0 + jj + 3];
    }
    part[prt][i] = (c0 + c1) + (c2 + c3);
    __syncthreads();
    if (tid < D_IDX) {
        float v = part[0][tid] + part[1][tid] + part[2][tid] + part[3][tid] + b1[tid];
        float r = v > 0.f ? v : 0.f;
        a_out[b * D_IDX + tid] = r;
        a_bf[b * D_IDX + tid] = f2bf_rne(r);
    }
}

// ---------------- Kernel S: fused convert + norms + MFMA bf16 screen ----------------
// chunkmin layout is TRANSPOSED: [chunk][query] so each wave's final store is one
// coalesced 2KB burst (round-4 layout scattered 4B writes at 16KB stride = ~16x
// sector amplification; suspected cause of the ~95us screen time).
__global__ __launch_bounds__(256) void k_screen(const float* __restrict__ keys,
                                                const unsigned short* __restrict__ ab,
                                                float* __restrict__ chunkmin) {
    __shared__ float cms[4][512];
    int lane = threadIdx.x & 63;
    int wid = threadIdx.x >> 6;
    int l15 = lane & 15, lg = lane >> 4;
    int mbase = blockIdx.x * 256 + wid * 64;
    int chunk = blockIdx.x * 4 + wid;

    bf16x8 kf[4][2];
    float nrm[4][4];
    #pragma unroll
    for (int t = 0; t < 4; ++t) {
        const float* rowp = keys + (size_t)(mbase + 16 * t + l15) * D_IDX;
        float4 f0 = *(const float4*)(rowp + lg * 8);
        float4 f1 = *(const float4*)(rowp + lg * 8 + 4);
        float4 f2 = *(const float4*)(rowp + 32 + lg * 8);
        float4 f3 = *(const float4*)(rowp + 32 + lg * 8 + 4);
        uint4 kp0, kp1;
        kp0.x = pack2bf(f0.x, f0.y); kp0.y = pack2bf(f0.z, f0.w);
        kp0.z = pack2bf(f1.x, f1.y); kp0.w = pack2bf(f1.z, f1.w);
        kp1.x = pack2bf(f2.x, f2.y); kp1.y = pack2bf(f2.z, f2.w);
        kp1.z = pack2bf(f3.x, f3.y); kp1.w = pack2bf(f3.z, f3.w);
        kf[t][0] = __builtin_bit_cast(bf16x8, kp0);
        kf[t][1] = __builtin_bit_cast(bf16x8, kp1);
        float s = f0.x*f0.x + f0.y*f0.y + f0.z*f0.z + f0.w*f0.w
                + f1.x*f1.x + f1.y*f1.y + f1.z*f1.z + f1.w*f1.w
                + f2.x*f2.x + f2.y*f2.y + f2.z*f2.z + f2.w*f2.w
                + f3.x*f3.x + f3.y*f3.y + f3.z*f3.z + f3.w*f3.w;
        s += __shfl_xor(s, 16, 64);
        s += __shfl_xor(s, 32, 64);   // full norm of row (mbase+16t+l15), replicated over lg
        s *= -0.5f;
        #pragma unroll
        for (int r = 0; r < 4; ++r)
            nrm[t][r] = __shfl(s, lg * 4 + r, 64);   // D-frag row lg*4+r held by lane lg*4+r
    }

    bf16x8 q0 = *(const bf16x8*)(ab + (size_t)l15 * D_IDX + lg * 8);
    bf16x8 q1 = *(const bf16x8*)(ab + (size_t)l15 * D_IDX + 32 + lg * 8);

    for (int qt = 0; qt < 32; ++qt) {
        bf16x8 c0 = q0, c1 = q1;
        if (qt < 31) {
            q0 = *(const bf16x8*)(ab + (size_t)((qt + 1) * 16 + l15) * D_IDX + lg * 8);
            q1 = *(const bf16x8*)(ab + (size_t)((qt + 1) * 16 + l15) * D_IDX + 32 + lg * 8);
        }
        f32x4 acc[4];
        #pragma unroll
        for (int t = 0; t < 4; ++t)
            acc[t] = (f32x4){nrm[t][0], nrm[t][1], nrm[t][2], nrm[t][3]};
        #pragma unroll
        for (int t = 0; t < 4; ++t)
            acc[t] = __builtin_amdgcn_mfma_f32_16x16x32_bf16(kf[t][0], c0, acc[t], 0, 0, 0);
        #pragma unroll
        for (int t = 0; t < 4; ++t)
            acc[t] = __builtin_amdgcn_mfma_f32_16x16x32_bf16(kf[t][1], c1, acc[t], 0, 0, 0);

        float t0 = fmaxf(fmaxf(acc[0][0], acc[0][1]), acc[0][2]);
        float t1 = fmaxf(fmaxf(acc[0][3], acc[1][0]), acc[1][1]);
        float t2 = fmaxf(fmaxf(acc[1][2], acc[1][3]), acc[2][0]);
        float t3 = fmaxf(fmaxf(acc[2][1], acc[2][2]), acc[2][3]);
        float t4 = fmaxf(fmaxf(acc[3][0], acc[3][1]), acc[3][2]);
        float mx = fmaxf(fmaxf(fmaxf(t0, t1), fmaxf(t2, t3)), fmaxf(t4, acc[3][3]));
        mx = fmaxf(mx, __shfl_xor(mx, 16, 64));
        mx = fmaxf(mx, __shfl_xor(mx, 32, 64));
        if (lane < 16) cms[wid][qt * 16 + lane] = -2.0f * mx;
    }
    // one coalesced 2KB store per wave (per-wave LDS row; same-wave ordering via lgkmcnt)
    float4 r0 = *(const float4*)&cms[wid][lane * 8];
    float4 r1 = *(const float4*)&cms[wid][lane * 8 + 4];
    float4* dst = (float4*)(chunkmin + (size_t)chunk * 512 + lane * 8);
    dst[0] = r0; dst[1] = r1;
}

// ---------------- Kernel R: exact fp32 refine (transposed chunkmin reads) ----------
__global__ __launch_bounds__(256) void k_refine(const float* __restrict__ chunkmin,
                                                const float* __restrict__ keys,
                                                const float* __restrict__ a_idx,
                                                unsigned long long* __restrict__ best) {
    int q = blockIdx.x, tid = threadIdx.x;
    __shared__ float a_s[D_IDX];
    __shared__ float red[256];
    __shared__ int list[256];
    __shared__ int cnt;
    if (tid < D_IDX) a_s[tid] = a_idx[q * D_IDX + tid];
    if (tid == 0) cnt = 0;
    float v[16];
    float lm = INFINITY;
    #pragma unroll
    for (int i = 0; i < 16; ++i) {
        v[i] = chunkmin[(size_t)(tid + 256 * i) * 512 + q];   // L2-resident strided read
        lm = fminf(lm, v[i]);
    }
    red[tid] = lm;
    __syncthreads();
    for (int s = 128; s > 0; s >>= 1) {
        if (tid < s) red[tid] = fminf(red[tid], red[tid + s]);
        __syncthreads();
    }
    float thrv = red[0] + MARGIN;
    #pragma unroll
    for (int i = 0; i < 16; ++i)
        if (v[i] <= thrv) { int p = atomicAdd(&cnt, 1); if (p < 256) list[p] = tid + 256 * i; }
    __syncthreads();
    int n = cnt > 256 ? 256 : cnt;
    int kq = tid >> 2, qtr = tid & 3;
    for (int e = 0; e < n; ++e) {
        int m = list[e] * 64 + kq;
        const float4* kp = (const float4*)(keys + (size_t)m * D_IDX + qtr * 16);
        const float4* av = (const float4*)(a_s + qtr * 16);
        float p = 0.f, p2 = 0.f;
        #pragma unroll
        for (int j = 0; j < 4; ++j) {
            float4 kv = kp[j], av4 = av[j];
            p  += kv.x * av4.x + kv.y * av4.y + kv.z * av4.z + kv.w * av4.w;
            p2 += kv.x * kv.x + kv.y * kv.y + kv.z * kv.z + kv.w * kv.w;
        }
        p  += __shfl_xor(p, 1, 64);  p  += __shfl_xor(p, 2, 64);
        p2 += __shfl_xor(p2, 1, 64); p2 += __shfl_xor(p2, 2, 64);
        if (qtr == 0) {
            float d = p2 - 2.0f * p;
            unsigned int db = __float_as_uint(d);
            unsigned int ok = (db & 0x80000000u) ? ~db : (db | 0x80000000u);
            atomicMin(best + q, ((unsigned long long)ok << 32) | (unsigned int)m);
        }
    }
}

// ---------------- Kernel C: gather + integrator + output (coalesced W2T/W3T) --------
__global__ __launch_bounds__(128) void k_tail(const float* __restrict__ a_idx,
                                              const unsigned long long* __restrict__ best,
                                              const float* __restrict__ mem_values,
                                              const float* __restrict__ w2t,
                                              const float* __restrict__ b2,
                                              const float* __restrict__ w3t,
                                              const float* __restrict__ b3,
                                              const float* __restrict__ W4,
                                              const float* __restrict__ b4,
                                              float* __restrict__ out) {
    int b = blockIdx.x, tid = threadIdx.x;
    __shared__ float xr[D_SENS];
    __shared__ float as[D_IDX];
    __shared__ float part[4][D_INT];
    __shared__ float ai[D_INT];
    unsigned int idx = (unsigned int)(best[b] & 0xFFFFFFFFull);
    const float* mv = mem_values + (size_t)idx * D_SENS;
    for (int j = tid; j < D_SENS; j += 128) xr[j] = mv[j];
    if (tid < D_IDX) as[tid] = a_idx[b * D_IDX + tid];
    __syncthreads();
    int i = tid & 31, prt = tid >> 5;
    int j0 = prt * 196;
    float c0 = 0.f, c1 = 0.f;
    #pragma unroll 2
    for (int jj = 0; jj < 196; jj += 2) {
        c0 += w3t[(j0 + jj + 0) * 32 + i] * xr[j0 + jj + 0];
        c1 += w3t[(j0 + jj + 1) * 32 + i] * xr[j0 + jj + 1];
    }
    float c2 = 0.f;
    int j2 = prt * 16;
    #pragma unroll
    for (int jj = 0; jj < 16; ++jj) c2 += w2t[(j2 + jj) * 32 + i] * as[j2 + jj];
    part[prt][i] = (c0 + c1) + c2;
    __syncthreads();
    if (tid < D_INT) {
        float acc = part[0][tid] + part[1][tid] + part[2][tid] + part[3][tid] + b2[tid] + b3[tid];
        ai[tid] = acc > 0.f ? acc : 0.f;
    }
    __syncthreads();
    if (tid < D_OUT) {
        float acc = b4[tid];
        const float* w4 = W4 + tid * D_INT;
        #pragma unroll
        for (int j = 0; j < D_INT; ++j) acc += w4[j] * ai[j];
        out[b * D_OUT + tid] = acc;
    }
}

// ---------------- Fallback fp32 kernels (proven round-1 structure) ----------------
__global__ void k_norms(const float* __restrict__ keys, float* __restrict__ norms) {
    int m = blockIdx.x * 256 + threadIdx.x;
    const float4* kp = (const float4*)(keys + (size_t)m * D_IDX);
    float a0 = 0.f, a1 = 0.f, a2 = 0.f, a3 = 0.f;
    #pragma unroll
    for (int t = 0; t < 16; t += 4) {
        float4 v0 = kp[t], v1 = kp[t + 1], v2 = kp[t + 2], v3 = kp[t + 3];
        a0 += v0.x * v0.x + v0.y * v0.y + v0.z * v0.z + v0.w * v0.w;
        a1 += v1.x * v1.x + v1.y * v1.y + v1.z * v1.z + v1.w * v1.w;
        a2 += v2.x * v2.x + v2.y * v2.y + v2.z * v2.z + v2.w * v2.w;
        a3 += v3.x * v3.x + v3.y * v3.y + v3.z * v3.z + v3.w * v3.w;
    }
    norms[m] = (a0 + a1) + (a2 + a3);
}

__global__ __launch_bounds__(256) void k_argmin(const float* __restrict__ keys,
                                                const float* __restrict__ norms,
                                                const float* __restrict__ a_idx,
                                                unsigned long long* __restrict__ best) {
    int q = blockIdx.y * 256 + threadIdx.x;
    float a[D_IDX];
    const float4* ap = (const float4*)(a_idx + (size_t)q * D_IDX);
    #pragma unroll
    for (int t = 0; t < 16; ++t) {
        float4 v = ap[t];
        a[4*t+0] = v.x; a[4*t+1] = v.y; a[4*t+2] = v.z; a[4*t+3] = v.w;
    }
    int m0 = blockIdx.x * 512;
    float bestd = INFINITY;
    int besti = 0;
    for (int i = 0; i < 512; ++i) {
        int m = m0 + i;
        const float* kp = keys + (size_t)m * D_IDX;
        float d0 = 0.f, d1 = 0.f, d2 = 0.f, d3 = 0.f;
        #pragma unroll
        for (int j = 0; j < D_IDX; j += 4) {
            d0 += kp[j+0] * a[j+0];
            d1 += kp[j+1] * a[j+1];
            d2 += kp[j+2] * a[j+2];
            d3 += kp[j+3] * a[j+3];
        }
        float dot = (d0 + d1) + (d2 + d3);
        float d = norms[m] - 2.0f * dot;
        if (d < bestd) { bestd = d; besti = m; }
    }
    unsigned int db = __float_as_uint(bestd);
    unsigned int okey = (db & 0x80000000u) ? ~db : (db | 0x80000000u);
    atomicMin(best + q, ((unsigned long long)okey << 32) | (unsigned int)besti);
}

extern "C" void kernel_launch(void* const* d_in, const int* in_sizes, int n_in,
                              void* d_out, int out_size, void* d_ws, size_t ws_size,
                              hipStream_t stream) {
    const float* x_sensory  = (const float*)d_in[0];
    const float* W1         = (const float*)d_in[1];
    const float* b1         = (const float*)d_in[2];
    const float* W2         = (const float*)d_in[3];
    const float* b2         = (const float*)d_in[4];
    const float* W3         = (const float*)d_in[5];
    const float* b3         = (const float*)d_in[6];
    const float* W4         = (const float*)d_in[7];
    const float* b4         = (const float*)d_in[8];
    const float* mem_keys   = (const float*)d_in[9];
    const float* mem_values = (const float*)d_in[10];
    float* out = (float*)d_out;

    // workspace layout
    char* ws = (char*)d_ws;
    unsigned long long* best = (unsigned long long*)ws;          // 4 KB @ 0
    float*          a_idx    = (float*)(ws + 4096);              // 128 KB
    unsigned short* a_bf     = (unsigned short*)(ws + 135168);   // 64 KB
    float*          W1T      = (float*)(ws + 200704);            // 196 KB
    float*          W2T      = (float*)(ws + 401408);            // 8 KB
    float*          W3T      = (float*)(ws + 409600);            // 98 KB
    float*          chunkmin = (float*)(ws + 524288);            // 8 MB  [chunk][query]
    const size_t NEEDED = 524288 + (size_t)B_SZ * NCHUNK * 4;    // ~8.9 MB

    if (ws_size >= NEEDED) {
        k_transpose<<<302, 256, 0, stream>>>(W1, W2, W3, W1T, W2T, W3T);
        k_indexer<<<B_SZ, 256, 0, stream>>>(x_sensory, W1T, b1, a_idx, a_bf, best);
        k_screen<<<M_ENT / 256, 256, 0, stream>>>(mem_keys, a_bf, chunkmin);
        k_refine<<<B_SZ, 256, 0, stream>>>(chunkmin, mem_keys, a_idx, best);
        k_tail<<<B_SZ, 128, 0, stream>>>(a_idx, best, mem_values, W2T, b2, W3T, b3, W4, b4, out);
    } else {
        // fallback: fp32 brute-force path
        float* norms = (float*)(ws + 524288);                    // 1 MB
        k_transpose<<<302, 256, 0, stream>>>(W1, W2, W3, W1T, W2T, W3T);
        k_indexer<<<B_SZ, 256, 0, stream>>>(x_sensory, W1T, b1, a_idx, a_bf, best);
        k_norms<<<M_ENT / 256, 256, 0, stream>>>(mem_keys, norms);
        k_argmin<<<dim3(M_ENT / 512, 2), 256, 0, stream>>>(mem_keys, norms, a_idx, best);
        k_tail<<<B_SZ, 128, 0, stream>>>(a_idx, best, mem_values, W2T, b2, W3T, b3, W4, b4, out);
    }
}

// Round 6
// 91.395 us; speedup vs baseline: 5.0645x; 1.1904x over previous
//
#include <hip/hip_runtime.h>
#include <stdint.h>

#define B_SZ   512
#define D_SENS 784
#define D_IDX  64
#define D_INT  32
#define D_OUT  10
#define M_ENT  262144
#define NCHUNK (M_ENT / 64)
#define MARGIN 1.5f

typedef __attribute__((ext_vector_type(8))) short bf16x8;
typedef __attribute__((ext_vector_type(4))) float f32x4;

__device__ inline unsigned short f2bf_rne(float f) {
    unsigned int u = __float_as_uint(f);
    unsigned int r = u + 0x7fffu + ((u >> 16) & 1u);
    return (unsigned short)(r >> 16);
}
// truncation pack: lo -> low16, hi -> high16 (1-2 VALU ops; rounding slack covered by MARGIN)
__device__ inline unsigned int pack2bf_t(float lo, float hi) {
    return (__float_as_uint(lo) >> 16) | (__float_as_uint(hi) & 0xFFFF0000u);
}

// ---------------- Kernel T: transpose W1, W2, W3 for coalesced reads ----------------
__global__ __launch_bounds__(256) void k_transpose(const float* __restrict__ W1,
                                                   const float* __restrict__ W2,
                                                   const float* __restrict__ W3,
                                                   float* __restrict__ W1T,
                                                   float* __restrict__ W2T,
                                                   float* __restrict__ W3T) {
    int idx = blockIdx.x * 256 + threadIdx.x;
    if (idx < 50176) {                       // 784*64
        int j = idx >> 6, i = idx & 63;
        W1T[idx] = W1[i * D_SENS + j];
    }
    int i2 = idx - 50176;
    if (i2 >= 0 && i2 < 2048) {              // 64*32
        int j = i2 >> 5, i = i2 & 31;
        W2T[i2] = W2[i * D_IDX + j];
    }
    int i3 = idx - 52224;
    if (i3 >= 0 && i3 < 25088) {             // 784*32
        int j = i3 >> 5, i = i3 & 31;
        W3T[i3] = W3[i * D_SENS + j];
    }
}

// ---------------- Kernel A: indexer layer (coalesced W1T) + bf16 copy + init best ----
__global__ __launch_bounds__(256) void k_indexer(const float* __restrict__ x,
                                                 const float* __restrict__ w1t,
                                                 const float* __restrict__ b1,
                                                 float* __restrict__ a_out,
                                                 unsigned short* __restrict__ a_bf,
                                                 unsigned long long* __restrict__ best) {
    int b = blockIdx.x, tid = threadIdx.x;
    __shared__ float xs[D_SENS];
    __shared__ float part[4][D_IDX];
    for (int j = tid; j < D_SENS; j += 256) xs[j] = x[b * D_SENS + j];
    if (tid == 0) best[b] = ~0ULL;
    __syncthreads();
    int i = tid & 63, prt = tid >> 6;
    int j0 = prt * 196;
    float c0 = 0.f, c1 = 0.f, c2 = 0.f, c3 = 0.f;
    #pragma unroll 4
    for (int jj = 0; jj < 196; jj += 4) {
        c0 += w1t[(j0 + jj + 0) * 64 + i] * xs[j0 + jj + 0];
        c1 += w1t[(j0 + jj + 1) * 64 + i] * xs[j0 + jj + 1];
        c2 += w1t[(j0 + jj + 2) * 64 + i] * xs[j0 + jj + 2];
        c3 += w1t[(j0 + jj + 3) * 64 + i] * xs[j0 + jj + 3];
    }
    part[prt][i] = (c0 + c1) + (c2 + c3);
    __syncthreads();
    if (tid < D_IDX) {
        float v = part[0][tid] + part[1][tid] + part[2][tid] + part[3][tid] + b1[tid];
        float r = v > 0.f ? v : 0.f;
        a_out[b * D_IDX + tid] = r;
        a_bf[b * D_IDX + tid] = f2bf_rne(r);
    }
}

// ---------------- Kernel S: MFMA screen, queries in swizzled LDS ----------------
// Block 256 = 4 waves; wave owns 128 keys (8 m-tiles of 16) in bf16 VGPR frags;
// all 512 queries staged once in LDS (64 KB, XOR-swizzled byte-col ^= (row&7)<<4).
// grid 512, 80KB LDS -> exactly 2 blocks/CU, one resident round.
// acc C-init comes straight from nrmv regs (no accvgpr init moves).
__global__ __launch_bounds__(256) void k_screen(const float* __restrict__ keys,
                                                const unsigned short* __restrict__ ab,
                                                float* __restrict__ chunkmin) {
    __shared__ unsigned short qlds[B_SZ * D_IDX];   // 64 KB
    __shared__ float cms[8][B_SZ];                  // 16 KB
    int tid = threadIdx.x;
    int lane = tid & 63, wid = tid >> 6;
    int l15 = lane & 15, lg = lane >> 4;

    // ---- stage queries: row r (128B), 16B chunk j, swizzled ----
    {
        int r = tid >> 3, j = tid & 7;
        #pragma unroll
        for (int pass = 0; pass < 16; ++pass, r += 32) {
            uint4 v = *(const uint4*)((const char*)ab + r * 128 + j * 16);
            int boff = r * 128 + ((j * 16) ^ ((r & 7) << 4));
            *(uint4*)((char*)qlds + boff) = v;
        }
    }

    // ---- load 128 keys/wave, convert (trunc) to frags, norms in-register ----
    int mbase = blockIdx.x * 512 + wid * 128;
    bf16x8 kf[8][2];
    f32x4 nrmv[8];
    #pragma unroll
    for (int t = 0; t < 8; ++t) {
        const float* rowp = keys + (size_t)(mbase + 16 * t + l15) * D_IDX;
        float4 f0 = *(const float4*)(rowp + lg * 8);
        float4 f1 = *(const float4*)(rowp + lg * 8 + 4);
        float4 f2 = *(const float4*)(rowp + 32 + lg * 8);
        float4 f3 = *(const float4*)(rowp + 32 + lg * 8 + 4);
        uint4 kp0, kp1;
        kp0.x = pack2bf_t(f0.x, f0.y); kp0.y = pack2bf_t(f0.z, f0.w);
        kp0.z = pack2bf_t(f1.x, f1.y); kp0.w = pack2bf_t(f1.z, f1.w);
        kp1.x = pack2bf_t(f2.x, f2.y); kp1.y = pack2bf_t(f2.z, f2.w);
        kp1.z = pack2bf_t(f3.x, f3.y); kp1.w = pack2bf_t(f3.z, f3.w);
        kf[t][0] = __builtin_bit_cast(bf16x8, kp0);
        kf[t][1] = __builtin_bit_cast(bf16x8, kp1);
        float s = f0.x*f0.x + f0.y*f0.y + f0.z*f0.z + f0.w*f0.w
                + f1.x*f1.x + f1.y*f1.y + f1.z*f1.z + f1.w*f1.w
                + f2.x*f2.x + f2.y*f2.y + f2.z*f2.z + f2.w*f2.w
                + f3.x*f3.x + f3.y*f3.y + f3.z*f3.z + f3.w*f3.w;
        s += __shfl_xor(s, 16, 64);
        s += __shfl_xor(s, 32, 64);     // full norm of row (mbase+16t+l15), replicated
        s *= -0.5f;
        float n0 = __shfl(s, lg * 4 + 0, 64);
        float n1 = __shfl(s, lg * 4 + 1, 64);
        float n2 = __shfl(s, lg * 4 + 2, 64);
        float n3 = __shfl(s, lg * 4 + 3, 64);
        nrmv[t] = (f32x4){n0, n1, n2, n3};
    }
    __syncthreads();

    // ---- q-loop over 32 tiles of 16 queries; operands all LDS/regs ----
    int colbase0 = lg * 16;          // k 0..31 fragment byte-col
    int colbase1 = 64 + lg * 16;     // k 32..63
    int rsw = (l15 & 7) << 4;
    int r0 = l15 * 128 + (colbase0 ^ rsw);
    int r1 = l15 * 128 + (colbase1 ^ rsw);
    bf16x8 q0 = *(const bf16x8*)((const char*)qlds + r0);
    bf16x8 q1 = *(const bf16x8*)((const char*)qlds + r1);

    for (int qt = 0; qt < 32; ++qt) {
        bf16x8 c0 = q0, c1 = q1;
        if (qt < 31) {
            q0 = *(const bf16x8*)((const char*)qlds + r0 + (qt + 1) * 2048);
            q1 = *(const bf16x8*)((const char*)qlds + r1 + (qt + 1) * 2048);
        }
        f32x4 acc[8];
        #pragma unroll
        for (int t = 0; t < 8; ++t)
            acc[t] = __builtin_amdgcn_mfma_f32_16x16x32_bf16(kf[t][0], c0, nrmv[t], 0, 0, 0);
        #pragma unroll
        for (int t = 0; t < 8; ++t)
            acc[t] = __builtin_amdgcn_mfma_f32_16x16x32_bf16(kf[t][1], c1, acc[t], 0, 0, 0);

        #pragma unroll
        for (int h = 0; h < 2; ++h) {
            int tb = h * 4;
            float t0 = fmaxf(fmaxf(acc[tb+0][0], acc[tb+0][1]), acc[tb+0][2]);
            float t1 = fmaxf(fmaxf(acc[tb+0][3], acc[tb+1][0]), acc[tb+1][1]);
            float t2 = fmaxf(fmaxf(acc[tb+1][2], acc[tb+1][3]), acc[tb+2][0]);
            float t3 = fmaxf(fmaxf(acc[tb+2][1], acc[tb+2][2]), acc[tb+2][3]);
            float t4 = fmaxf(fmaxf(acc[tb+3][0], acc[tb+3][1]), acc[tb+3][2]);
            float mx = fmaxf(fmaxf(fmaxf(t0, t1), fmaxf(t2, t3)), fmaxf(t4, acc[tb+3][3]));
            mx = fmaxf(mx, __shfl_xor(mx, 16, 64));
            mx = fmaxf(mx, __shfl_xor(mx, 32, 64));
            if (lane < 16) cms[wid * 2 + h][qt * 16 + lane] = -2.0f * mx;
        }
    }

    // ---- per-wave coalesced 2KB-row stores (same-wave LDS data, no barrier) ----
    #pragma unroll
    for (int h = 0; h < 2; ++h) {
        int row = wid * 2 + h;
        float4 s0 = *(const float4*)&cms[row][lane * 8];
        float4 s1 = *(const float4*)&cms[row][lane * 8 + 4];
        float4* dst = (float4*)(chunkmin + (size_t)(blockIdx.x * 8 + row) * B_SZ + lane * 8);
        dst[0] = s0; dst[1] = s1;
    }
}

// ---------------- Kernel X: transpose chunkmin [chunk][q] -> [q][chunk] ----------
__global__ __launch_bounds__(256) void k_cmT(const float* __restrict__ src,
                                             float* __restrict__ dst) {
    __shared__ float t[64][65];
    int c0 = blockIdx.x * 64, q0 = blockIdx.y * 64;
    int j = threadIdx.x & 63, i0 = threadIdx.x >> 6;
    #pragma unroll
    for (int k = 0; k < 16; ++k) {
        int i = i0 + k * 4;
        t[i][j] = src[(size_t)(c0 + i) * B_SZ + q0 + j];
    }
    __syncthreads();
    #pragma unroll
    for (int k = 0; k < 16; ++k) {
        int i = i0 + k * 4;
        dst[(size_t)(q0 + i) * NCHUNK + c0 + j] = t[j][i];
    }
}

// ---------------- Kernel R: exact fp32 refine (coalesced chunkminT reads) ----------
__global__ __launch_bounds__(256) void k_refine(const float* __restrict__ chunkminT,
                                                const float* __restrict__ keys,
                                                const float* __restrict__ a_idx,
                                                unsigned long long* __restrict__ best) {
    int q = blockIdx.x, tid = threadIdx.x;
    __shared__ float a_s[D_IDX];
    __shared__ float red[256];
    __shared__ int list[256];
    __shared__ int cnt;
    if (tid < D_IDX) a_s[tid] = a_idx[q * D_IDX + tid];
    if (tid == 0) cnt = 0;
    const float* wrow = chunkminT + (size_t)q * NCHUNK;
    float v[16];
    float lm = INFINITY;
    #pragma unroll
    for (int i = 0; i < 16; ++i) { v[i] = wrow[tid + 256 * i]; lm = fminf(lm, v[i]); }
    red[tid] = lm;
    __syncthreads();
    for (int s = 128; s > 0; s >>= 1) {
        if (tid < s) red[tid] = fminf(red[tid], red[tid + s]);
        __syncthreads();
    }
    float thrv = red[0] + MARGIN;
    #pragma unroll
    for (int i = 0; i < 16; ++i)
        if (v[i] <= thrv) { int p = atomicAdd(&cnt, 1); if (p < 256) list[p] = tid + 256 * i; }
    __syncthreads();
    int n = cnt > 256 ? 256 : cnt;
    int kq = tid >> 2, qtr = tid & 3;
    for (int e = 0; e < n; ++e) {
        int m = list[e] * 64 + kq;
        const float4* kp = (const float4*)(keys + (size_t)m * D_IDX + qtr * 16);
        const float4* av = (const float4*)(a_s + qtr * 16);
        float p = 0.f, p2 = 0.f;
        #pragma unroll
        for (int j = 0; j < 4; ++j) {
            float4 kv = kp[j], av4 = av[j];
            p  += kv.x * av4.x + kv.y * av4.y + kv.z * av4.z + kv.w * av4.w;
            p2 += kv.x * kv.x + kv.y * kv.y + kv.z * kv.z + kv.w * kv.w;
        }
        p  += __shfl_xor(p, 1, 64);  p  += __shfl_xor(p, 2, 64);
        p2 += __shfl_xor(p2, 1, 64); p2 += __shfl_xor(p2, 2, 64);
        if (qtr == 0) {
            float d = p2 - 2.0f * p;
            unsigned int db = __float_as_uint(d);
            unsigned int ok = (db & 0x80000000u) ? ~db : (db | 0x80000000u);
            atomicMin(best + q, ((unsigned long long)ok << 32) | (unsigned int)m);
        }
    }
}

// ---------------- Kernel C: gather + integrator + output (coalesced W2T/W3T) --------
__global__ __launch_bounds__(128) void k_tail(const float* __restrict__ a_idx,
                                              const unsigned long long* __restrict__ best,
                                              const float* __restrict__ mem_values,
                                              const float* __restrict__ w2t,
                                              const float* __restrict__ b2,
                                              const float* __restrict__ w3t,
                                              const float* __restrict__ b3,
                                              const float* __restrict__ W4,
                                              const float* __restrict__ b4,
                                              float* __restrict__ out) {
    int b = blockIdx.x, tid = threadIdx.x;
    __shared__ float xr[D_SENS];
    __shared__ float as[D_IDX];
    __shared__ float part[4][D_INT];
    __shared__ float ai[D_INT];
    unsigned int idx = (unsigned int)(best[b] & 0xFFFFFFFFull);
    const float* mv = mem_values + (size_t)idx * D_SENS;
    for (int j = tid; j < D_SENS; j += 128) xr[j] = mv[j];
    if (tid < D_IDX) as[tid] = a_idx[b * D_IDX + tid];
    __syncthreads();
    int i = tid & 31, prt = tid >> 5;
    int j0 = prt * 196;
    float c0 = 0.f, c1 = 0.f;
    #pragma unroll 2
    for (int jj = 0; jj < 196; jj += 2) {
        c0 += w3t[(j0 + jj + 0) * 32 + i] * xr[j0 + jj + 0];
        c1 += w3t[(j0 + jj + 1) * 32 + i] * xr[j0 + jj + 1];
    }
    float c2 = 0.f;
    int j2 = prt * 16;
    #pragma unroll
    for (int jj = 0; jj < 16; ++jj) c2 += w2t[(j2 + jj) * 32 + i] * as[j2 + jj];
    part[prt][i] = (c0 + c1) + c2;
    __syncthreads();
    if (tid < D_INT) {
        float acc = part[0][tid] + part[1][tid] + part[2][tid] + part[3][tid] + b2[tid] + b3[tid];
        ai[tid] = acc > 0.f ? acc : 0.f;
    }
    __syncthreads();
    if (tid < D_OUT) {
        float acc = b4[tid];
        const float* w4 = W4 + tid * D_INT;
        #pragma unroll
        for (int j = 0; j < D_INT; ++j) acc += w4[j] * ai[j];
        out[b * D_OUT + tid] = acc;
    }
}

// ---------------- Fallback fp32 kernels (proven round-1 structure) ----------------
__global__ void k_norms(const float* __restrict__ keys, float* __restrict__ norms) {
    int m = blockIdx.x * 256 + threadIdx.x;
    const float4* kp = (const float4*)(keys + (size_t)m * D_IDX);
    float a0 = 0.f, a1 = 0.f, a2 = 0.f, a3 = 0.f;
    #pragma unroll
    for (int t = 0; t < 16; t += 4) {
        float4 v0 = kp[t], v1 = kp[t + 1], v2 = kp[t + 2], v3 = kp[t + 3];
        a0 += v0.x * v0.x + v0.y * v0.y + v0.z * v0.z + v0.w * v0.w;
        a1 += v1.x * v1.x + v1.y * v1.y + v1.z * v1.z + v1.w * v1.w;
        a2 += v2.x * v2.x + v2.y * v2.y + v2.z * v2.z + v2.w * v2.w;
        a3 += v3.x * v3.x + v3.y * v3.y + v3.z * v3.z + v3.w * v3.w;
    }
    norms[m] = (a0 + a1) + (a2 + a3);
}

__global__ __launch_bounds__(256) void k_argmin(const float* __restrict__ keys,
                                                const float* __restrict__ norms,
                                                const float* __restrict__ a_idx,
                                                unsigned long long* __restrict__ best) {
    int q = blockIdx.y * 256 + threadIdx.x;
    float a[D_IDX];
    const float4* ap = (const float4*)(a_idx + (size_t)q * D_IDX);
    #pragma unroll
    for (int t = 0; t < 16; ++t) {
        float4 v = ap[t];
        a[4*t+0] = v.x; a[4*t+1] = v.y; a[4*t+2] = v.z; a[4*t+3] = v.w;
    }
    int m0 = blockIdx.x * 512;
    float bestd = INFINITY;
    int besti = 0;
    for (int i = 0; i < 512; ++i) {
        int m = m0 + i;
        const float* kp = keys + (size_t)m * D_IDX;
        float d0 = 0.f, d1 = 0.f, d2 = 0.f, d3 = 0.f;
        #pragma unroll
        for (int j = 0; j < D_IDX; j += 4) {
            d0 += kp[j+0] * a[j+0];
            d1 += kp[j+1] * a[j+1];
            d2 += kp[j+2] * a[j+2];
            d3 += kp[j+3] * a[j+3];
        }
        float dot = (d0 + d1) + (d2 + d3);
        float d = norms[m] - 2.0f * dot;
        if (d < bestd) { bestd = d; besti = m; }
    }
    unsigned int db = __float_as_uint(bestd);
    unsigned int okey = (db & 0x80000000u) ? ~db : (db | 0x80000000u);
    atomicMin(best + q, ((unsigned long long)okey << 32) | (unsigned int)besti);
}

extern "C" void kernel_launch(void* const* d_in, const int* in_sizes, int n_in,
                              void* d_out, int out_size, void* d_ws, size_t ws_size,
                              hipStream_t stream) {
    const float* x_sensory  = (const float*)d_in[0];
    const float* W1         = (const float*)d_in[1];
    const float* b1         = (const float*)d_in[2];
    const float* W2         = (const float*)d_in[3];
    const float* b2         = (const float*)d_in[4];
    const float* W3         = (const float*)d_in[5];
    const float* b3         = (const float*)d_in[6];
    const float* W4         = (const float*)d_in[7];
    const float* b4         = (const float*)d_in[8];
    const float* mem_keys   = (const float*)d_in[9];
    const float* mem_values = (const float*)d_in[10];
    float* out = (float*)d_out;

    // workspace layout
    char* ws = (char*)d_ws;
    unsigned long long* best = (unsigned long long*)ws;           // 4 KB @ 0
    float*          a_idx     = (float*)(ws + 4096);              // 128 KB
    unsigned short* a_bf      = (unsigned short*)(ws + 135168);   // 64 KB
    float*          W1T       = (float*)(ws + 200704);            // 196 KB
    float*          W2T       = (float*)(ws + 401408);            // 8 KB
    float*          W3T       = (float*)(ws + 409600);            // 98 KB
    float*          chunkmin  = (float*)(ws + 524288);            // 8 MB  [chunk][query]
    float*          chunkminT = (float*)(ws + 8912896);           // 8 MB  [query][chunk]
    const size_t NEEDED = 17301504;

    if (ws_size >= NEEDED) {
        k_transpose<<<302, 256, 0, stream>>>(W1, W2, W3, W1T, W2T, W3T);
        k_indexer<<<B_SZ, 256, 0, stream>>>(x_sensory, W1T, b1, a_idx, a_bf, best);
        k_screen<<<M_ENT / 512, 256, 0, stream>>>(mem_keys, a_bf, chunkmin);
        k_cmT<<<dim3(NCHUNK / 64, B_SZ / 64), 256, 0, stream>>>(chunkmin, chunkminT);
        k_refine<<<B_SZ, 256, 0, stream>>>(chunkminT, mem_keys, a_idx, best);
        k_tail<<<B_SZ, 128, 0, stream>>>(a_idx, best, mem_values, W2T, b2, W3T, b3, W4, b4, out);
    } else {
        // fallback: fp32 brute-force path
        float* norms = (float*)(ws + 524288);                     // 1 MB
        k_transpose<<<302, 256, 0, stream>>>(W1, W2, W3, W1T, W2T, W3T);
        k_indexer<<<B_SZ, 256, 0, stream>>>(x_sensory, W1T, b1, a_idx, a_bf, best);
        k_norms<<<M_ENT / 256, 256, 0, stream>>>(mem_keys, norms);
        k_argmin<<<dim3(M_ENT / 512, 2), 256, 0, stream>>>(mem_keys, norms, a_idx, best);
        k_tail<<<B_SZ, 128, 0, stream>>>(a_idx, best, mem_values, W2T, b2, W3T, b3, W4, b4, out);
    }
}

// Round 7
// 62.420 us; speedup vs baseline: 7.4154x; 1.4642x over previous
//
#include <hip/hip_runtime.h>
#include <stdint.h>

#define B_SZ   512
#define D_SENS 784
#define D_IDX  64
#define D_INT  32
#define D_OUT  10
#define M_ENT  262144
#define NCHUNK (M_ENT / 64)
#define MARGIN 1.5f

typedef __attribute__((ext_vector_type(8))) short bf16x8;
typedef __attribute__((ext_vector_type(4))) float f32x4;

__device__ inline unsigned short f2bf_rne(float f) {
    unsigned int u = __float_as_uint(f);
    unsigned int r = u + 0x7fffu + ((u >> 16) & 1u);
    return (unsigned short)(r >> 16);
}
// truncation pack: lo -> low16, hi -> high16 (error covered by MARGIN; refine is exact)
__device__ inline unsigned int pack2bf_t(float lo, float hi) {
    return (__float_as_uint(lo) >> 16) | (__float_as_uint(hi) & 0xFFFF0000u);
}

// ---------------- Kernel F: indexer (no transpose needed) + bf16 copy + best init ----
// thread (i=tid>>2, sub=tid&3): 4 lanes per output row, float4 reads of W1 row
// (64B contiguous per row-quad; W1 is 200KB -> L2-resident). 4-lane shfl reduce.
__global__ __launch_bounds__(256) void k_front(const float* __restrict__ x,
                                               const float* __restrict__ W1,
                                               const float* __restrict__ b1,
                                               float* __restrict__ a_out,
                                               unsigned short* __restrict__ a_bf,
                                               unsigned long long* __restrict__ best) {
    int b = blockIdx.x, tid = threadIdx.x;
    __shared__ float xs[D_SENS];
    if (tid < 196) ((float4*)xs)[tid] = ((const float4*)(x + (size_t)b * D_SENS))[tid];
    if (tid == 0) best[b] = ~0ULL;
    __syncthreads();
    int i = tid >> 2, sub = tid & 3;
    const float4* wr = (const float4*)(W1 + (size_t)i * D_SENS);
    const float4* xs4 = (const float4*)xs;
    float a0 = 0.f, a1 = 0.f, a2 = 0.f, a3 = 0.f;
    #pragma unroll 7
    for (int jj = 0; jj < 49; ++jj) {
        float4 w = wr[sub + 4 * jj];
        float4 xv = xs4[sub + 4 * jj];
        a0 += w.x * xv.x; a1 += w.y * xv.y; a2 += w.z * xv.z; a3 += w.w * xv.w;
    }
    float s = (a0 + a1) + (a2 + a3);
    s += __shfl_xor(s, 1, 64);
    s += __shfl_xor(s, 2, 64);
    if (sub == 0) {
        float v = s + b1[i];
        float r = v > 0.f ? v : 0.f;
        a_out[b * D_IDX + i] = r;
        a_bf[b * D_IDX + i] = f2bf_rne(r);
    }
}

// ---------------- Kernel S: MFMA screen, queries in swizzled LDS (proven R6) --------
__global__ __launch_bounds__(256) void k_screen(const float* __restrict__ keys,
                                                const unsigned short* __restrict__ ab,
                                                float* __restrict__ chunkmin) {
    __shared__ unsigned short qlds[B_SZ * D_IDX];   // 64 KB
    __shared__ float cms[8][B_SZ];                  // 16 KB
    int tid = threadIdx.x;
    int lane = tid & 63, wid = tid >> 6;
    int l15 = lane & 15, lg = lane >> 4;

    // stage queries: row r (128B), 16B chunk j, XOR-swizzled
    {
        int r = tid >> 3, j = tid & 7;
        #pragma unroll
        for (int pass = 0; pass < 16; ++pass, r += 32) {
            uint4 v = *(const uint4*)((const char*)ab + r * 128 + j * 16);
            int boff = r * 128 + ((j * 16) ^ ((r & 7) << 4));
            *(uint4*)((char*)qlds + boff) = v;
        }
    }

    // 128 keys/wave -> bf16 frags + norms in-register
    int mbase = blockIdx.x * 512 + wid * 128;
    bf16x8 kf[8][2];
    f32x4 nrmv[8];
    #pragma unroll
    for (int t = 0; t < 8; ++t) {
        const float* rowp = keys + (size_t)(mbase + 16 * t + l15) * D_IDX;
        float4 f0 = *(const float4*)(rowp + lg * 8);
        float4 f1 = *(const float4*)(rowp + lg * 8 + 4);
        float4 f2 = *(const float4*)(rowp + 32 + lg * 8);
        float4 f3 = *(const float4*)(rowp + 32 + lg * 8 + 4);
        uint4 kp0, kp1;
        kp0.x = pack2bf_t(f0.x, f0.y); kp0.y = pack2bf_t(f0.z, f0.w);
        kp0.z = pack2bf_t(f1.x, f1.y); kp0.w = pack2bf_t(f1.z, f1.w);
        kp1.x = pack2bf_t(f2.x, f2.y); kp1.y = pack2bf_t(f2.z, f2.w);
        kp1.z = pack2bf_t(f3.x, f3.y); kp1.w = pack2bf_t(f3.z, f3.w);
        kf[t][0] = __builtin_bit_cast(bf16x8, kp0);
        kf[t][1] = __builtin_bit_cast(bf16x8, kp1);
        float s = f0.x*f0.x + f0.y*f0.y + f0.z*f0.z + f0.w*f0.w
                + f1.x*f1.x + f1.y*f1.y + f1.z*f1.z + f1.w*f1.w
                + f2.x*f2.x + f2.y*f2.y + f2.z*f2.z + f2.w*f2.w
                + f3.x*f3.x + f3.y*f3.y + f3.z*f3.z + f3.w*f3.w;
        s += __shfl_xor(s, 16, 64);
        s += __shfl_xor(s, 32, 64);
        s *= -0.5f;
        float n0 = __shfl(s, lg * 4 + 0, 64);
        float n1 = __shfl(s, lg * 4 + 1, 64);
        float n2 = __shfl(s, lg * 4 + 2, 64);
        float n3 = __shfl(s, lg * 4 + 3, 64);
        nrmv[t] = (f32x4){n0, n1, n2, n3};
    }
    __syncthreads();

    int colbase0 = lg * 16;
    int colbase1 = 64 + lg * 16;
    int rsw = (l15 & 7) << 4;
    int r0 = l15 * 128 + (colbase0 ^ rsw);
    int r1 = l15 * 128 + (colbase1 ^ rsw);
    bf16x8 q0 = *(const bf16x8*)((const char*)qlds + r0);
    bf16x8 q1 = *(const bf16x8*)((const char*)qlds + r1);

    for (int qt = 0; qt < 32; ++qt) {
        bf16x8 c0 = q0, c1 = q1;
        if (qt < 31) {
            q0 = *(const bf16x8*)((const char*)qlds + r0 + (qt + 1) * 2048);
            q1 = *(const bf16x8*)((const char*)qlds + r1 + (qt + 1) * 2048);
        }
        f32x4 acc[8];
        #pragma unroll
        for (int t = 0; t < 8; ++t)
            acc[t] = __builtin_amdgcn_mfma_f32_16x16x32_bf16(kf[t][0], c0, nrmv[t], 0, 0, 0);
        #pragma unroll
        for (int t = 0; t < 8; ++t)
            acc[t] = __builtin_amdgcn_mfma_f32_16x16x32_bf16(kf[t][1], c1, acc[t], 0, 0, 0);

        #pragma unroll
        for (int h = 0; h < 2; ++h) {
            int tb = h * 4;
            float t0 = fmaxf(fmaxf(acc[tb+0][0], acc[tb+0][1]), acc[tb+0][2]);
            float t1 = fmaxf(fmaxf(acc[tb+0][3], acc[tb+1][0]), acc[tb+1][1]);
            float t2 = fmaxf(fmaxf(acc[tb+1][2], acc[tb+1][3]), acc[tb+2][0]);
            float t3 = fmaxf(fmaxf(acc[tb+2][1], acc[tb+2][2]), acc[tb+2][3]);
            float t4 = fmaxf(fmaxf(acc[tb+3][0], acc[tb+3][1]), acc[tb+3][2]);
            float mx = fmaxf(fmaxf(fmaxf(t0, t1), fmaxf(t2, t3)), fmaxf(t4, acc[tb+3][3]));
            mx = fmaxf(mx, __shfl_xor(mx, 16, 64));
            mx = fmaxf(mx, __shfl_xor(mx, 32, 64));
            if (lane < 16) cms[wid * 2 + h][qt * 16 + lane] = -2.0f * mx;
        }
    }
    #pragma unroll
    for (int h = 0; h < 2; ++h) {
        int row = wid * 2 + h;
        float4 s0 = *(const float4*)&cms[row][lane * 8];
        float4 s1 = *(const float4*)&cms[row][lane * 8 + 4];
        float4* dst = (float4*)(chunkmin + (size_t)(blockIdx.x * 8 + row) * B_SZ + lane * 8);
        dst[0] = s0; dst[1] = s1;
    }
}

// ---------------- Kernel B: fused filter + exact refine + gather + MLP tail ---------
// block q. chunkmin==nullptr => fallback mode (read bestg instead of filtering).
__global__ __launch_bounds__(256) void k_back(const float* __restrict__ chunkmin,
                                              const float* __restrict__ keys,
                                              const float* __restrict__ a_idx,
                                              const unsigned long long* __restrict__ bestg,
                                              const float* __restrict__ mem_values,
                                              const float* __restrict__ W2,
                                              const float* __restrict__ b2,
                                              const float* __restrict__ W3,
                                              const float* __restrict__ b3,
                                              const float* __restrict__ W4,
                                              const float* __restrict__ b4,
                                              float* __restrict__ out) {
    int q = blockIdx.x, tid = threadIdx.x;
    int lane = tid & 63;
    __shared__ float a_s[D_IDX];
    __shared__ float red[256];
    __shared__ int list[256];
    __shared__ int cnt;
    __shared__ unsigned long long bestsh;
    __shared__ float xr[D_SENS];
    __shared__ float ai[D_INT];

    if (tid < 16) ((float4*)a_s)[tid] = ((const float4*)(a_idx + q * D_IDX))[tid];
    if (tid == 0) { cnt = 0; bestsh = ~0ULL; }
    __syncthreads();

    if (chunkmin != nullptr) {
        // ---- phase 1a: filter chunks (strided L2 reads of [chunk][q] matrix) ----
        float v[16];
        float lm = INFINITY;
        #pragma unroll
        for (int i = 0; i < 16; ++i) {
            v[i] = chunkmin[(size_t)(tid + 256 * i) * B_SZ + q];
            lm = fminf(lm, v[i]);
        }
        red[tid] = lm;
        __syncthreads();
        for (int s = 128; s > 0; s >>= 1) {
            if (tid < s) red[tid] = fminf(red[tid], red[tid + s]);
            __syncthreads();
        }
        float thrv = red[0] + MARGIN;
        #pragma unroll
        for (int i = 0; i < 16; ++i)
            if (v[i] <= thrv) { int p = atomicAdd(&cnt, 1); if (p < 256) list[p] = tid + 256 * i; }
        __syncthreads();
        int n = cnt > 256 ? 256 : cnt;

        // ---- phase 1b: exact fp32 distances, block-local packed argmin ----
        unsigned long long bestp = ~0ULL;
        int kq = tid >> 2, qtr = tid & 3;
        for (int e = 0; e < n; ++e) {
            int m = list[e] * 64 + kq;
            const float4* kp = (const float4*)(keys + (size_t)m * D_IDX + qtr * 16);
            const float4* av = (const float4*)(a_s + qtr * 16);
            float p = 0.f, p2 = 0.f;
            #pragma unroll
            for (int j = 0; j < 4; ++j) {
                float4 kv = kp[j], av4 = av[j];
                p  += kv.x * av4.x + kv.y * av4.y + kv.z * av4.z + kv.w * av4.w;
                p2 += kv.x * kv.x + kv.y * kv.y + kv.z * kv.z + kv.w * kv.w;
            }
            p  += __shfl_xor(p, 1, 64);  p  += __shfl_xor(p, 2, 64);
            p2 += __shfl_xor(p2, 1, 64); p2 += __shfl_xor(p2, 2, 64);
            if (qtr == 0) {
                float d = p2 - 2.0f * p;
                unsigned int db = __float_as_uint(d);
                unsigned int ok = (db & 0x80000000u) ? ~db : (db | 0x80000000u);
                unsigned long long packed = ((unsigned long long)ok << 32) | (unsigned int)m;
                bestp = packed < bestp ? packed : bestp;
            }
        }
        #pragma unroll
        for (int off = 32; off >= 1; off >>= 1) {
            unsigned long long o = __shfl_xor(bestp, off, 64);
            bestp = o < bestp ? o : bestp;
        }
        if (lane == 0) atomicMin(&bestsh, bestp);
        __syncthreads();
    } else {
        if (tid == 0) bestsh = bestg[q];
        __syncthreads();
    }

    // ---- phase 2: gather + integrator + output ----
    unsigned int idx = (unsigned int)(bestsh & 0xFFFFFFFFull);
    if (tid < 196) ((float4*)xr)[tid] = ((const float4*)(mem_values + (size_t)idx * D_SENS))[tid];
    __syncthreads();

    int i = tid >> 3, sub = tid & 7;           // 32 outputs x 8 sub-lanes
    const float* w3r = W3 + (size_t)i * D_SENS;
    float a0 = 0.f, a1 = 0.f, a2 = 0.f, a3 = 0.f;
    #pragma unroll 6
    for (int jj = 0; jj < 24; ++jj) {
        float4 w = *(const float4*)(w3r + sub * 4 + 32 * jj);
        float4 xv = *(const float4*)(xr + sub * 4 + 32 * jj);
        a0 += w.x * xv.x; a1 += w.y * xv.y; a2 += w.z * xv.z; a3 += w.w * xv.w;
    }
    if (sub < 4) {                              // tail 768..783
        float4 w = *(const float4*)(w3r + 768 + sub * 4);
        float4 xv = *(const float4*)(xr + 768 + sub * 4);
        a0 += w.x * xv.x; a1 += w.y * xv.y; a2 += w.z * xv.z; a3 += w.w * xv.w;
    }
    const float* w2r = W2 + (size_t)i * D_IDX;
    #pragma unroll
    for (int jj = 0; jj < 2; ++jj) {
        float4 w = *(const float4*)(w2r + sub * 4 + 32 * jj);
        float4 av = *(const float4*)(a_s + sub * 4 + 32 * jj);
        a0 += w.x * av.x; a1 += w.y * av.y; a2 += w.z * av.z; a3 += w.w * av.w;
    }
    float s = (a0 + a1) + (a2 + a3);
    s += __shfl_xor(s, 1, 64);
    s += __shfl_xor(s, 2, 64);
    s += __shfl_xor(s, 4, 64);
    if (sub == 0) {
        float acc = s + b2[i] + b3[i];
        ai[i] = acc > 0.f ? acc : 0.f;
    }
    __syncthreads();
    if (tid < D_OUT) {
        float acc = b4[tid];
        const float* w4 = W4 + tid * D_INT;
        #pragma unroll
        for (int j = 0; j < D_INT; ++j) acc += w4[j] * ai[j];
        out[q * D_OUT + tid] = acc;
    }
}

// ---------------- Fallback fp32 kernels (proven) ----------------
__global__ void k_norms(const float* __restrict__ keys, float* __restrict__ norms) {
    int m = blockIdx.x * 256 + threadIdx.x;
    const float4* kp = (const float4*)(keys + (size_t)m * D_IDX);
    float a0 = 0.f, a1 = 0.f, a2 = 0.f, a3 = 0.f;
    #pragma unroll
    for (int t = 0; t < 16; t += 4) {
        float4 v0 = kp[t], v1 = kp[t + 1], v2 = kp[t + 2], v3 = kp[t + 3];
        a0 += v0.x * v0.x + v0.y * v0.y + v0.z * v0.z + v0.w * v0.w;
        a1 += v1.x * v1.x + v1.y * v1.y + v1.z * v1.z + v1.w * v1.w;
        a2 += v2.x * v2.x + v2.y * v2.y + v2.z * v2.z + v2.w * v2.w;
        a3 += v3.x * v3.x + v3.y * v3.y + v3.z * v3.z + v3.w * v3.w;
    }
    norms[m] = (a0 + a1) + (a2 + a3);
}

__global__ __launch_bounds__(256) void k_argmin(const float* __restrict__ keys,
                                                const float* __restrict__ norms,
                                                const float* __restrict__ a_idx,
                                                unsigned long long* __restrict__ best) {
    int q = blockIdx.y * 256 + threadIdx.x;
    float a[D_IDX];
    const float4* ap = (const float4*)(a_idx + (size_t)q * D_IDX);
    #pragma unroll
    for (int t = 0; t < 16; ++t) {
        float4 v = ap[t];
        a[4*t+0] = v.x; a[4*t+1] = v.y; a[4*t+2] = v.z; a[4*t+3] = v.w;
    }
    int m0 = blockIdx.x * 512;
    float bestd = INFINITY;
    int besti = 0;
    for (int i = 0; i < 512; ++i) {
        int m = m0 + i;
        const float* kp = keys + (size_t)m * D_IDX;
        float d0 = 0.f, d1 = 0.f, d2 = 0.f, d3 = 0.f;
        #pragma unroll
        for (int j = 0; j < D_IDX; j += 4) {
            d0 += kp[j+0] * a[j+0];
            d1 += kp[j+1] * a[j+1];
            d2 += kp[j+2] * a[j+2];
            d3 += kp[j+3] * a[j+3];
        }
        float dot = (d0 + d1) + (d2 + d3);
        float d = norms[m] - 2.0f * dot;
        if (d < bestd) { bestd = d; besti = m; }
    }
    unsigned int db = __float_as_uint(bestd);
    unsigned int okey = (db & 0x80000000u) ? ~db : (db | 0x80000000u);
    atomicMin(best + q, ((unsigned long long)okey << 32) | (unsigned int)besti);
}

extern "C" void kernel_launch(void* const* d_in, const int* in_sizes, int n_in,
                              void* d_out, int out_size, void* d_ws, size_t ws_size,
                              hipStream_t stream) {
    const float* x_sensory  = (const float*)d_in[0];
    const float* W1         = (const float*)d_in[1];
    const float* b1         = (const float*)d_in[2];
    const float* W2         = (const float*)d_in[3];
    const float* b2         = (const float*)d_in[4];
    const float* W3         = (const float*)d_in[5];
    const float* b3         = (const float*)d_in[6];
    const float* W4         = (const float*)d_in[7];
    const float* b4         = (const float*)d_in[8];
    const float* mem_keys   = (const float*)d_in[9];
    const float* mem_values = (const float*)d_in[10];
    float* out = (float*)d_out;

    // workspace layout
    char* ws = (char*)d_ws;
    unsigned long long* best = (unsigned long long*)ws;          // 4 KB @ 0
    float*          a_idx    = (float*)(ws + 4096);              // 128 KB
    unsigned short* a_bf     = (unsigned short*)(ws + 135168);   // 64 KB
    float*          chunkmin = (float*)(ws + 200704);            // 8 MB  [chunk][query]
    const size_t NEEDED = 200704 + (size_t)NCHUNK * B_SZ * 4;    // ~8.6 MB

    if (ws_size >= NEEDED) {
        k_front<<<B_SZ, 256, 0, stream>>>(x_sensory, W1, b1, a_idx, a_bf, best);
        k_screen<<<M_ENT / 512, 256, 0, stream>>>(mem_keys, a_bf, chunkmin);
        k_back<<<B_SZ, 256, 0, stream>>>(chunkmin, mem_keys, a_idx, nullptr, mem_values,
                                         W2, b2, W3, b3, W4, b4, out);
    } else {
        // fallback: fp32 brute-force path (~1.2 MB)
        float* norms = (float*)(ws + 200704);
        k_front<<<B_SZ, 256, 0, stream>>>(x_sensory, W1, b1, a_idx, a_bf, best);
        k_norms<<<M_ENT / 256, 256, 0, stream>>>(mem_keys, norms);
        k_argmin<<<dim3(M_ENT / 512, 2), 256, 0, stream>>>(mem_keys, norms, a_idx, best);
        k_back<<<B_SZ, 256, 0, stream>>>(nullptr, mem_keys, a_idx, best, mem_values,
                                         W2, b2, W3, b3, W4, b4, out);
    }
}